// Round 1
// baseline (1046.349 us; speedup 1.0000x reference)
//
#include <hip/hip_runtime.h>
#include <math.h>

// MultiHeadAttention: B=4,S=2048,D=1024,H=16,DK=64
// Round 7: stage 3 outproj converted to fp16 hi/lo MFMA (3-term split),
//   same verified tile structure as proj_mfma. Stages 0-2 unchanged.
//   stage 1: proj_mfma  q/k/v = X @ W[h] via 16x16x32 f16 MFMA, 3-term split
//   stage 2: attn  fp16 MFMA flash attention
//   stage 3: outproj_mfma  out = cat @ Wo^T + bo via same MFMA split
// Verified 16x16x32 layouts: A[m=ln][k=quad*8+j], B-frag needs [n][k-contig]
// LDS rows, C/D col=ln, row=quad*4+r.

#define BB 4
#define SS 2048
#define DD 1024
#define HH 16
#define DKK 64
#define MM (BB * SS) // 8192

typedef unsigned short u16;
typedef _Float16 f16x8 __attribute__((ext_vector_type(8)));
typedef float f32x4 __attribute__((ext_vector_type(4)));

__device__ __forceinline__ float bf2f(u16 u) {
    union { unsigned int i; float f; } c;
    c.i = ((unsigned int)u) << 16;
    return c.f;
}
__device__ __forceinline__ u16 f2h(float f) {
    _Float16 h = (_Float16)f; // RNE
    return __builtin_bit_cast(u16, h);
}

// ---------------- stage 0: dtype sniffer (insurance) ----------------
__global__ void sniff_kernel(const u16* t0, const u16* t1, const u16* t2,
                             const u16* t3, const u16* t4, const u16* t5,
                             const u16* t6, const u16* t7, int* flags)
{
    const u16* ptrs[8] = {t0, t1, t2, t3, t4, t5, t6, t7};
    const u16* p = ptrs[blockIdx.x];
    int tid = threadIdx.x; // 64
    int cnt = 0;
    #pragma unroll
    for (int i = 0; i < 8; i++) {
        u16 v = p[tid * 8 + i];
        int e = (v >> 7) & 0xFF;
        if (e >= 0xF0 || (e <= 0x0F && (v & 0x7FFF) != 0)) cnt++;
    }
    #pragma unroll
    for (int off = 32; off; off >>= 1) cnt += __shfl_down(cnt, off);
    if (tid == 0) flags[blockIdx.x] = (cnt >= 4) ? 1 : 0;
}

// ---------------- stage 1: MFMA projections (hi/lo split) ----------------
// grid: (MM/128, H, 3), block 256 (4 waves). Wave w: rows w*32..+31.
// K-chunks of 64. LDS: Xhi/Xlo [128][72], Whi/Wlo [64n][72k] (transposed).
// k-swizzle: 8-elem group g stored at g ^ (row&7) to break staging conflicts.
__global__ __launch_bounds__(256) void proj_mfma_kernel(
    const void* __restrict__ Q, const void* __restrict__ K, const void* __restrict__ V,
    const void* __restrict__ Wq, const void* __restrict__ Wk, const void* __restrict__ Wv,
    const int* __restrict__ flags,
    u16* __restrict__ qb, u16* __restrict__ kb, u16* __restrict__ vb)
{
    const int z = blockIdx.z;
    const void* __restrict__ X = (z == 0) ? Q : (z == 1) ? K : V;
    const void* __restrict__ W = (z == 0) ? Wq : (z == 1) ? Wk : Wv;
    u16* __restrict__ out      = (z == 0) ? qb : (z == 1) ? kb : vb;
    const int xf = flags[z];
    const int wf = flags[3 + z];
    const int h  = blockIdx.y;
    const int m0 = blockIdx.x * 128;

    __shared__ __align__(16) u16 Xh[128 * 72];
    __shared__ __align__(16) u16 Xl[128 * 72];
    __shared__ __align__(16) u16 Wh[64 * 72];
    __shared__ __align__(16) u16 Wl[64 * 72];

    const int tid  = threadIdx.x;
    const int lane = tid & 63, wave = tid >> 6;
    const int quad = lane >> 4, ln = lane & 15;

    // staging maps
    const int trow = tid >> 1, tseg = (tid & 1) * 32; // X: 32 k-elems/thread
    const int wn = tid & 63, wkq = (tid >> 6) * 16;   // W: 16 k-elems/thread

    f32x4 acc[2][4];
    #pragma unroll
    for (int mh = 0; mh < 2; mh++)
        #pragma unroll
        for (int nt = 0; nt < 4; nt++)
            acc[mh][nt] = (f32x4){0.f, 0.f, 0.f, 0.f};

    for (int kbase = 0; kbase < DD; kbase += 64) {
        __syncthreads();
        // ---- stage X tile 128m x 64k -> hi/lo fp16, swizzled ----
        const int xsw = (trow & 7) << 3;
        #pragma unroll
        for (int i = 0; i < 8; i++) {
            float x4[4];
            if (xf) {
                float4 v = *(const float4*)((const float*)X +
                    (size_t)(m0 + trow) * DD + kbase + tseg + 4 * i);
                x4[0] = v.x; x4[1] = v.y; x4[2] = v.z; x4[3] = v.w;
            } else {
                ushort4 v = *(const ushort4*)((const u16*)X +
                    (size_t)(m0 + trow) * DD + kbase + tseg + 4 * i);
                x4[0] = bf2f(v.x); x4[1] = bf2f(v.y); x4[2] = bf2f(v.z); x4[3] = bf2f(v.w);
            }
            ushort4 h4, l4;
            {
                _Float16 hh;
                hh = (_Float16)x4[0]; h4.x = __builtin_bit_cast(u16, hh);
                l4.x = f2h(x4[0] - (float)hh);
                hh = (_Float16)x4[1]; h4.y = __builtin_bit_cast(u16, hh);
                l4.y = f2h(x4[1] - (float)hh);
                hh = (_Float16)x4[2]; h4.z = __builtin_bit_cast(u16, hh);
                l4.z = f2h(x4[2] - (float)hh);
                hh = (_Float16)x4[3]; h4.w = __builtin_bit_cast(u16, hh);
                l4.w = f2h(x4[3] - (float)hh);
            }
            int kcol = tseg + 4 * i;
            int kphys = (kcol & 7) | ((kcol ^ xsw) & 56);
            *(ushort4*)&Xh[trow * 72 + kphys] = h4;
            *(ushort4*)&Xl[trow * 72 + kphys] = l4;
        }
        // ---- stage W tile 64k x 64n -> transposed [n][k] hi/lo, swizzled ----
        const int wsw = (wn & 7) << 3;
        #pragma unroll
        for (int j = 0; j < 4; j++) {
            float w4[4];
            #pragma unroll
            for (int jj = 0; jj < 4; jj++) {
                int kk = kbase + wkq + 4 * j + jj;
                if (wf)
                    w4[jj] = ((const float*)W)[(size_t)h * DD * DKK + (size_t)kk * DKK + wn];
                else
                    w4[jj] = bf2f(((const u16*)W)[(size_t)h * DD * DKK + (size_t)kk * DKK + wn]);
            }
            ushort4 h4, l4;
            {
                _Float16 hh;
                hh = (_Float16)w4[0]; h4.x = __builtin_bit_cast(u16, hh);
                l4.x = f2h(w4[0] - (float)hh);
                hh = (_Float16)w4[1]; h4.y = __builtin_bit_cast(u16, hh);
                l4.y = f2h(w4[1] - (float)hh);
                hh = (_Float16)w4[2]; h4.z = __builtin_bit_cast(u16, hh);
                l4.z = f2h(w4[2] - (float)hh);
                hh = (_Float16)w4[3]; h4.w = __builtin_bit_cast(u16, hh);
                l4.w = f2h(w4[3] - (float)hh);
            }
            int kcol = wkq + 4 * j;
            int kphys = (kcol & 7) | ((kcol ^ wsw) & 56);
            *(ushort4*)&Wh[wn * 72 + kphys] = h4;
            *(ushort4*)&Wl[wn * 72 + kphys] = l4;
        }
        __syncthreads();

        // ---- compute: 2 k-halves x 4 n-tiles x 2 m-halves x 3 MFMAs ----
        #pragma unroll
        for (int kh = 0; kh < 2; kh++) {
            f16x8 ah[2], al[2];
            #pragma unroll
            for (int mh = 0; mh < 2; mh++) {
                int row = wave * 32 + mh * 16 + ln;
                int kgrp = (((kh * 4 + quad) ^ (row & 7)) << 3);
                ah[mh] = __builtin_bit_cast(f16x8, *(const uint4*)&Xh[row * 72 + kgrp]);
                al[mh] = __builtin_bit_cast(f16x8, *(const uint4*)&Xl[row * 72 + kgrp]);
            }
            #pragma unroll
            for (int nt = 0; nt < 4; nt++) {
                int n = nt * 16 + ln;
                int kgrp = (((kh * 4 + quad) ^ (n & 7)) << 3);
                f16x8 bh = __builtin_bit_cast(f16x8, *(const uint4*)&Wh[n * 72 + kgrp]);
                f16x8 bl = __builtin_bit_cast(f16x8, *(const uint4*)&Wl[n * 72 + kgrp]);
                #pragma unroll
                for (int mh = 0; mh < 2; mh++) {
                    acc[mh][nt] = __builtin_amdgcn_mfma_f32_16x16x32_f16(al[mh], bh, acc[mh][nt], 0, 0, 0);
                    acc[mh][nt] = __builtin_amdgcn_mfma_f32_16x16x32_f16(ah[mh], bl, acc[mh][nt], 0, 0, 0);
                    acc[mh][nt] = __builtin_amdgcn_mfma_f32_16x16x32_f16(ah[mh], bh, acc[mh][nt], 0, 0, 0);
                }
            }
        }
    }

    // ---- epilogue: fp16 store to [B,H,S,DK] ----
    #pragma unroll
    for (int mh = 0; mh < 2; mh++)
        #pragma unroll
        for (int r = 0; r < 4; r++) {
            int m = m0 + wave * 32 + mh * 16 + quad * 4 + r;
            int b = m >> 11, s = m & 2047;
            u16* op = out + (((size_t)(b * HH + h) * SS + s)) * DKK;
            #pragma unroll
            for (int nt = 0; nt < 4; nt++)
                op[nt * 16 + ln] = f2h(acc[mh][nt][r]);
        }
}

// ---------------- stage 2: fp16 MFMA flash attention (unchanged) ----------------
__global__ __launch_bounds__(256) void attn_kernel(
    const u16* __restrict__ qb, const u16* __restrict__ kb,
    const u16* __restrict__ vb, float* __restrict__ cat)
{
    __shared__ __align__(16) u16 Kt[64 * 72];
    __shared__ __align__(16) u16 Vt[64 * 72];
    __shared__ __align__(16) u16 Pw[4][16 * 72];

    const int tid  = threadIdx.x;
    const int lane = tid & 63, wave = tid >> 6;
    const int quad = lane >> 4, ln = lane & 15;
    const int xt = (SS / 64 - 1) - blockIdx.x; // heavy tiles first
    const int bh = blockIdx.y;
    const int qbase = xt * 64;

    const u16* qp = qb + ((size_t)bh * SS + qbase + wave * 16 + ln) * DKK;
    f16x8 qf0 = __builtin_bit_cast(f16x8, *(const uint4*)(qp + quad * 8));
    f16x8 qf1 = __builtin_bit_cast(f16x8, *(const uint4*)(qp + 32 + quad * 8));

    f32x4 acc[4];
    #pragma unroll
    for (int n = 0; n < 4; n++) acc[n] = (f32x4){0.f, 0.f, 0.f, 0.f};
    float mrow[4], lrow[4];
    #pragma unroll
    for (int r = 0; r < 4; r++) { mrow[r] = -INFINITY; lrow[r] = 0.f; }

    const int skey = tid >> 2, sseg = (tid & 3) * 16;
    const int vkey = tid & 63, vdkb = (tid >> 6) * 16;

    for (int kt = 0; kt <= xt; ++kt) {
        __syncthreads();
        {
            const u16* ksrc = kb + ((size_t)bh * SS + kt * 64 + skey) * DKK + sseg;
            uint4 a = *(const uint4*)ksrc;
            uint4 b = *(const uint4*)(ksrc + 8);
            *(uint4*)&Kt[skey * 72 + sseg] = a;
            *(uint4*)&Kt[skey * 72 + sseg + 8] = b;

            const u16* vsrc = vb + ((size_t)bh * SS + kt * 64 + vkey) * DKK + vdkb;
            u16 vv[16];
            *(uint4*)&vv[0] = *(const uint4*)vsrc;
            *(uint4*)&vv[8] = *(const uint4*)(vsrc + 8);
            #pragma unroll
            for (int i = 0; i < 16; i++)
                Vt[(vdkb + i) * 72 + vkey] = vv[i];
        }
        __syncthreads();

        f32x4 sa[4];
        #pragma unroll
        for (int n = 0; n < 4; n++) {
            sa[n] = (f32x4){0.f, 0.f, 0.f, 0.f};
            f16x8 kf0 = __builtin_bit_cast(f16x8,
                *(const uint4*)&Kt[(n * 16 + ln) * 72 + quad * 8]);
            sa[n] = __builtin_amdgcn_mfma_f32_16x16x32_f16(qf0, kf0, sa[n], 0, 0, 0);
            f16x8 kf1 = __builtin_bit_cast(f16x8,
                *(const uint4*)&Kt[(n * 16 + ln) * 72 + 32 + quad * 8]);
            sa[n] = __builtin_amdgcn_mfma_f32_16x16x32_f16(qf1, kf1, sa[n], 0, 0, 0);
        }

        float sc[4][4];
        const bool diag = (kt == xt);
        #pragma unroll
        for (int n = 0; n < 4; n++)
            #pragma unroll
            for (int r = 0; r < 4; r++) {
                float s = sa[n][r] * 8.0f;
                if (diag && (n * 16 + ln) > (wave * 16 + quad * 4 + r))
                    s = -INFINITY;
                sc[n][r] = s;
            }

        float rmax[4];
        #pragma unroll
        for (int r = 0; r < 4; r++)
            rmax[r] = fmaxf(fmaxf(sc[0][r], sc[1][r]), fmaxf(sc[2][r], sc[3][r]));
        #pragma unroll
        for (int off = 1; off < 16; off <<= 1)
            #pragma unroll
            for (int r = 0; r < 4; r++)
                rmax[r] = fmaxf(rmax[r], __shfl_xor(rmax[r], off));
        float alpha[4];
        #pragma unroll
        for (int r = 0; r < 4; r++) {
            float mn = fmaxf(mrow[r], rmax[r]);
            alpha[r] = __expf(mrow[r] - mn);
            mrow[r] = mn;
        }
        u16* pw = Pw[wave];
        float lsum[4] = {0.f, 0.f, 0.f, 0.f};
        #pragma unroll
        for (int n = 0; n < 4; n++)
            #pragma unroll
            for (int r = 0; r < 4; r++) {
                float p = __expf(sc[n][r] - mrow[r]);
                _Float16 ph = (_Float16)p;
                pw[(quad * 4 + r) * 72 + n * 16 + ln] = __builtin_bit_cast(u16, ph);
                lsum[r] += (float)ph;
            }
        #pragma unroll
        for (int off = 1; off < 16; off <<= 1)
            #pragma unroll
            for (int r = 0; r < 4; r++)
                lsum[r] += __shfl_xor(lsum[r], off);
        #pragma unroll
        for (int r = 0; r < 4; r++)
            lrow[r] = lrow[r] * alpha[r] + lsum[r];
        #pragma unroll
        for (int n = 0; n < 4; n++)
            #pragma unroll
            for (int r = 0; r < 4; r++)
                acc[n][r] *= alpha[r];

        asm volatile("s_waitcnt lgkmcnt(0)" ::: "memory"); // wave-local RAW
        f16x8 pf0 = __builtin_bit_cast(f16x8, *(const uint4*)&pw[ln * 72 + quad * 8]);
        f16x8 pf1 = __builtin_bit_cast(f16x8, *(const uint4*)&pw[ln * 72 + 32 + quad * 8]);

        #pragma unroll
        for (int n = 0; n < 4; n++) {
            f16x8 vf0 = __builtin_bit_cast(f16x8,
                *(const uint4*)&Vt[(n * 16 + ln) * 72 + quad * 8]);
            acc[n] = __builtin_amdgcn_mfma_f32_16x16x32_f16(pf0, vf0, acc[n], 0, 0, 0);
            f16x8 vf1 = __builtin_bit_cast(f16x8,
                *(const uint4*)&Vt[(n * 16 + ln) * 72 + 32 + quad * 8]);
            acc[n] = __builtin_amdgcn_mfma_f32_16x16x32_f16(pf1, vf1, acc[n], 0, 0, 0);
        }
    }

    const int b = bh >> 4, h = bh & 15;
    #pragma unroll
    for (int r = 0; r < 4; r++) {
        float inv = 1.0f / lrow[r];
        int row = qbase + wave * 16 + quad * 4 + r;
        float* op = cat + ((size_t)b * SS + row) * DD + h * DKK;
        #pragma unroll
        for (int n = 0; n < 4; n++)
            op[n * 16 + ln] = acc[n][r] * inv;
    }
}

// ---------------- stage 3: MFMA output projection (hi/lo split) ----------------
// out[m][n] = sum_k cat[m][k] * Wo[n][k] + bo[n]  (Wo row-major [n][k] — already
// the B-frag layout). grid (MM/128, DD/64), block 256. Same tile/swizzle
// structure as proj_mfma_kernel.
__global__ __launch_bounds__(256) void outproj_mfma_kernel(
    const float* __restrict__ A, const void* __restrict__ Wo,
    const void* __restrict__ bo, const int* __restrict__ flags,
    float* __restrict__ out)
{
    const int wf = flags[6];
    const int bf = flags[7];
    const int m0 = blockIdx.x * 128;
    const int n0 = blockIdx.y * 64;

    __shared__ __align__(16) u16 Xh[128 * 72];
    __shared__ __align__(16) u16 Xl[128 * 72];
    __shared__ __align__(16) u16 Wh[64 * 72];
    __shared__ __align__(16) u16 Wl[64 * 72];

    const int tid  = threadIdx.x;
    const int lane = tid & 63, wave = tid >> 6;
    const int quad = lane >> 4, ln = lane & 15;

    // staging maps
    const int trow = tid >> 1, tseg = (tid & 1) * 32; // X: 32 k-elems/thread
    const int wrow = tid >> 2, wseg = (tid & 3) * 16; // W: 16 k-elems/thread (row-major)

    f32x4 acc[2][4];
    #pragma unroll
    for (int mh = 0; mh < 2; mh++)
        #pragma unroll
        for (int nt = 0; nt < 4; nt++)
            acc[mh][nt] = (f32x4){0.f, 0.f, 0.f, 0.f};

    for (int kbase = 0; kbase < DD; kbase += 64) {
        __syncthreads();
        // ---- stage X (cat, always fp32) 128m x 64k -> hi/lo fp16, swizzled ----
        const int xsw = (trow & 7) << 3;
        #pragma unroll
        for (int i = 0; i < 8; i++) {
            float4 v = *(const float4*)(A +
                (size_t)(m0 + trow) * DD + kbase + tseg + 4 * i);
            float x4[4] = {v.x, v.y, v.z, v.w};
            ushort4 h4, l4;
            {
                _Float16 hh;
                hh = (_Float16)x4[0]; h4.x = __builtin_bit_cast(u16, hh);
                l4.x = f2h(x4[0] - (float)hh);
                hh = (_Float16)x4[1]; h4.y = __builtin_bit_cast(u16, hh);
                l4.y = f2h(x4[1] - (float)hh);
                hh = (_Float16)x4[2]; h4.z = __builtin_bit_cast(u16, hh);
                l4.z = f2h(x4[2] - (float)hh);
                hh = (_Float16)x4[3]; h4.w = __builtin_bit_cast(u16, hh);
                l4.w = f2h(x4[3] - (float)hh);
            }
            int kcol = tseg + 4 * i;
            int kphys = (kcol & 7) | ((kcol ^ xsw) & 56);
            *(ushort4*)&Xh[trow * 72 + kphys] = h4;
            *(ushort4*)&Xl[trow * 72 + kphys] = l4;
        }
        // ---- stage W tile: Wo[n0+wrow][kbase+wseg..+15] (row-major, no transpose) ----
        const int wsw = (wrow & 7) << 3;
        #pragma unroll
        for (int j = 0; j < 4; j++) {
            float w4[4];
            if (wf) {
                float4 v = *(const float4*)((const float*)Wo +
                    (size_t)(n0 + wrow) * DD + kbase + wseg + 4 * j);
                w4[0] = v.x; w4[1] = v.y; w4[2] = v.z; w4[3] = v.w;
            } else {
                ushort4 v = *(const ushort4*)((const u16*)Wo +
                    (size_t)(n0 + wrow) * DD + kbase + wseg + 4 * j);
                w4[0] = bf2f(v.x); w4[1] = bf2f(v.y); w4[2] = bf2f(v.z); w4[3] = bf2f(v.w);
            }
            ushort4 h4, l4;
            {
                _Float16 hh;
                hh = (_Float16)w4[0]; h4.x = __builtin_bit_cast(u16, hh);
                l4.x = f2h(w4[0] - (float)hh);
                hh = (_Float16)w4[1]; h4.y = __builtin_bit_cast(u16, hh);
                l4.y = f2h(w4[1] - (float)hh);
                hh = (_Float16)w4[2]; h4.z = __builtin_bit_cast(u16, hh);
                l4.z = f2h(w4[2] - (float)hh);
                hh = (_Float16)w4[3]; h4.w = __builtin_bit_cast(u16, hh);
                l4.w = f2h(w4[3] - (float)hh);
            }
            int kcol = wseg + 4 * j;
            int kphys = (kcol & 7) | ((kcol ^ wsw) & 56);
            *(ushort4*)&Wh[wrow * 72 + kphys] = h4;
            *(ushort4*)&Wl[wrow * 72 + kphys] = l4;
        }
        __syncthreads();

        // ---- compute: 2 k-halves x 4 n-tiles x 2 m-halves x 3 MFMAs ----
        #pragma unroll
        for (int kh = 0; kh < 2; kh++) {
            f16x8 ah[2], al[2];
            #pragma unroll
            for (int mh = 0; mh < 2; mh++) {
                int row = wave * 32 + mh * 16 + ln;
                int kgrp = (((kh * 4 + quad) ^ (row & 7)) << 3);
                ah[mh] = __builtin_bit_cast(f16x8, *(const uint4*)&Xh[row * 72 + kgrp]);
                al[mh] = __builtin_bit_cast(f16x8, *(const uint4*)&Xl[row * 72 + kgrp]);
            }
            #pragma unroll
            for (int nt = 0; nt < 4; nt++) {
                int n = nt * 16 + ln;
                int kgrp = (((kh * 4 + quad) ^ (n & 7)) << 3);
                f16x8 bh = __builtin_bit_cast(f16x8, *(const uint4*)&Wh[n * 72 + kgrp]);
                f16x8 bl = __builtin_bit_cast(f16x8, *(const uint4*)&Wl[n * 72 + kgrp]);
                #pragma unroll
                for (int mh = 0; mh < 2; mh++) {
                    acc[mh][nt] = __builtin_amdgcn_mfma_f32_16x16x32_f16(al[mh], bh, acc[mh][nt], 0, 0, 0);
                    acc[mh][nt] = __builtin_amdgcn_mfma_f32_16x16x32_f16(ah[mh], bl, acc[mh][nt], 0, 0, 0);
                    acc[mh][nt] = __builtin_amdgcn_mfma_f32_16x16x32_f16(ah[mh], bh, acc[mh][nt], 0, 0, 0);
                }
            }
        }
    }

    // ---- epilogue: bias add + fp32 store ----
    float bias[4];
    #pragma unroll
    for (int nt = 0; nt < 4; nt++) {
        int n = n0 + nt * 16 + ln;
        bias[nt] = bf ? ((const float*)bo)[n] : bf2f(((const u16*)bo)[n]);
    }
    #pragma unroll
    for (int mh = 0; mh < 2; mh++)
        #pragma unroll
        for (int r = 0; r < 4; r++) {
            int m = m0 + wave * 32 + mh * 16 + quad * 4 + r;
            float* op = out + (size_t)m * DD + n0;
            #pragma unroll
            for (int nt = 0; nt < 4; nt++)
                op[nt * 16 + ln] = acc[mh][nt][r] + bias[nt];
        }
}

extern "C" void kernel_launch(void* const* d_in, const int* in_sizes, int n_in,
                              void* d_out, int out_size, void* d_ws, size_t ws_size,
                              hipStream_t stream)
{
    const void* Q = d_in[0];
    const void* K = d_in[1];
    const void* V = d_in[2];
    const int widx = (n_in >= 9) ? 4 : 3; // mask present iff n_in >= 9 (ignored)
    const void* Wq = d_in[widx + 0];
    const void* Wk = d_in[widx + 1];
    const void* Wv = d_in[widx + 2];
    const void* Wo = d_in[widx + 3];
    const void* bo = d_in[widx + 4];
    float* out = (float*)d_out;

    const size_t per = (size_t)BB * HH * SS * DKK; // 8,388,608 elements
    u16* qb = (u16*)d_ws;
    u16* kb = qb + per;
    u16* vb = kb + per;
    float* cat = (float*)(vb + per);
    int* flags = (int*)(cat + per);

    sniff_kernel<<<8, 64, 0, stream>>>(
        (const u16*)Q, (const u16*)K, (const u16*)V,
        (const u16*)Wq, (const u16*)Wk, (const u16*)Wv,
        (const u16*)Wo, (const u16*)bo, flags);

    dim3 g1(MM / 128, HH, 3);
    proj_mfma_kernel<<<g1, 256, 0, stream>>>(Q, K, V, Wq, Wk, Wv, flags, qb, kb, vb);

    dim3 g2(SS / 64, BB * HH);
    attn_kernel<<<g2, 256, 0, stream>>>(qb, kb, vb, cat);

    dim3 g3(MM / 128, DD / 64);
    outproj_mfma_kernel<<<g3, 256, 0, stream>>>(cat, Wo, bo, flags, out);
}

// Round 2
// 759.138 us; speedup vs baseline: 1.3783x; 1.3783x over previous
//
#include <hip/hip_runtime.h>
#include <math.h>

// MultiHeadAttention: B=4,S=2048,D=1024,H=16,DK=64
// Round 8: proj/outproj rebuilt around pre-split fp16 hi/lo operands.
//   stage 0: sniff (dtype insurance)
//   stage 0.5: split_x / split_wqkv — one-time fp32(bf16) -> fp16 hi/lo split
//              (X row-major [8192][1024]; W transposed to [z][h][n][k])
//   stage 1: proj_v2 — A-frags direct global->VGPR (row/lane = 64B line,
//            coalesced, L2-resident); W via global_load_lds into XOR-swizzled
//            conflict-free LDS (phys group = g ^ (row&7), 128B rows).
//            48 MFMA (16x16x32 f16, 3-term split) per 64-K chunk per wave.
//   stage 2: attn — fp16 MFMA flash attention (epilogue now writes cat as
//            fp16 hi/lo pair; bit-identical to previous in-kernel split)
//   stage 3: outproj_v2 — same structure as proj_v2, fp32 out + bias
// Verified 16x16x32 layouts: A[m=ln][k=quad*8+j], B-frag [n][k-contig],
// C/D col=ln, row=quad*4+r.

#define BB 4
#define SS 2048
#define DD 1024
#define HH 16
#define DKK 64
#define MM (BB * SS) // 8192

typedef unsigned short u16;
typedef _Float16 f16x8 __attribute__((ext_vector_type(8)));
typedef float f32x4 __attribute__((ext_vector_type(4)));
typedef __attribute__((address_space(1))) unsigned int gas_u32;
typedef __attribute__((address_space(3))) unsigned int las_u32;

__device__ __forceinline__ float bf2f(u16 u) {
    union { unsigned int i; float f; } c;
    c.i = ((unsigned int)u) << 16;
    return c.f;
}
__device__ __forceinline__ u16 f2h(float f) {
    _Float16 h = (_Float16)f; // RNE
    return __builtin_bit_cast(u16, h);
}
__device__ __forceinline__ void split1(float x, u16& hi, u16& lo) {
    _Float16 hh = (_Float16)x;
    hi = __builtin_bit_cast(u16, hh);
    lo = f2h(x - (float)hh);
}
// global(16B/lane) -> LDS at wave-uniform base + lane*16
__device__ __forceinline__ void gld16(const void* g, void* l) {
    __builtin_amdgcn_global_load_lds((gas_u32*)g, (las_u32*)l, 16, 0, 0);
}

// ---------------- stage 0: dtype sniffer (insurance) ----------------
__global__ void sniff_kernel(const u16* t0, const u16* t1, const u16* t2,
                             const u16* t3, const u16* t4, const u16* t5,
                             const u16* t6, const u16* t7, int* flags)
{
    const u16* ptrs[8] = {t0, t1, t2, t3, t4, t5, t6, t7};
    const u16* p = ptrs[blockIdx.x];
    int tid = threadIdx.x; // 64
    int cnt = 0;
    #pragma unroll
    for (int i = 0; i < 8; i++) {
        u16 v = p[tid * 8 + i];
        int e = (v >> 7) & 0xFF;
        if (e >= 0xF0 || (e <= 0x0F && (v & 0x7FFF) != 0)) cnt++;
    }
    #pragma unroll
    for (int off = 32; off; off >>= 1) cnt += __shfl_down(cnt, off);
    if (tid == 0) flags[blockIdx.x] = (cnt >= 4) ? 1 : 0;
}

// ---------------- stage 0.5a: elementwise hi/lo split (X and Wo) ----------------
// grid: n_elems/2048 blocks, 256 threads, 8 elems/thread.
__global__ __launch_bounds__(256) void split_x_kernel(
    const void* __restrict__ X, const int* __restrict__ flags, int fidx,
    u16* __restrict__ Xh, u16* __restrict__ Xl)
{
    const int xf = flags[fidx];
    size_t idx = ((size_t)blockIdx.x * 256 + threadIdx.x) * 8;
    float x[8];
    if (xf) {
        float4 a = *(const float4*)((const float*)X + idx);
        float4 b = *(const float4*)((const float*)X + idx + 4);
        x[0] = a.x; x[1] = a.y; x[2] = a.z; x[3] = a.w;
        x[4] = b.x; x[5] = b.y; x[6] = b.z; x[7] = b.w;
    } else {
        ushort4 a = *(const ushort4*)((const u16*)X + idx);
        ushort4 b = *(const ushort4*)((const u16*)X + idx + 4);
        x[0] = bf2f(a.x); x[1] = bf2f(a.y); x[2] = bf2f(a.z); x[3] = bf2f(a.w);
        x[4] = bf2f(b.x); x[5] = bf2f(b.y); x[6] = bf2f(b.z); x[7] = bf2f(b.w);
    }
    union { u16 u[8]; uint4 v; } H, L;
    #pragma unroll
    for (int i = 0; i < 8; i++) split1(x[i], H.u[i], L.u[i]);
    *(uint4*)(Xh + idx) = H.v;
    *(uint4*)(Xl + idx) = L.v;
}

// ---------------- stage 0.5b: Wq/Wk/Wv transpose + split ----------------
// source [z][h][k][n] (k-major) -> dest [z][h][n][k] fp16 hi/lo.
// grid (DD/64, HH, 3), block 256: per-block 64k x 64n tile.
__global__ __launch_bounds__(256) void split_wqkv_kernel(
    const void* __restrict__ Wq, const void* __restrict__ Wk, const void* __restrict__ Wv,
    const int* __restrict__ flags, u16* __restrict__ Wth, u16* __restrict__ Wtl)
{
    const int z = blockIdx.z, h = blockIdx.y, kc = blockIdx.x;
    const void* __restrict__ W = (z == 0) ? Wq : (z == 1) ? Wk : Wv;
    const int wf = flags[3 + z];
    __shared__ float T[64][65];
    const int t = threadIdx.x;
    {
        const int kk = t >> 2, ns = (t & 3) * 16;
        const size_t base = (size_t)h * DD * DKK + (size_t)(kc * 64 + kk) * DKK + ns;
        #pragma unroll
        for (int j = 0; j < 4; j++) {
            if (wf) {
                float4 v = *(const float4*)((const float*)W + base + 4 * j);
                T[kk][ns + 4 * j + 0] = v.x; T[kk][ns + 4 * j + 1] = v.y;
                T[kk][ns + 4 * j + 2] = v.z; T[kk][ns + 4 * j + 3] = v.w;
            } else {
                ushort4 v = *(const ushort4*)((const u16*)W + base + 4 * j);
                T[kk][ns + 4 * j + 0] = bf2f(v.x); T[kk][ns + 4 * j + 1] = bf2f(v.y);
                T[kk][ns + 4 * j + 2] = bf2f(v.z); T[kk][ns + 4 * j + 3] = bf2f(v.w);
            }
        }
    }
    __syncthreads();
    {
        const int n = t >> 2, ks = (t & 3) * 16;
        union { u16 u[16]; uint4 v[2]; } Hv, Lv;
        #pragma unroll
        for (int i = 0; i < 16; i++) split1(T[ks + i][n], Hv.u[i], Lv.u[i]);
        size_t ob = ((size_t)(z * HH + h) * DKK + n) * DD + kc * 64 + ks;
        *(uint4*)(Wth + ob)     = Hv.v[0];
        *(uint4*)(Wth + ob + 8) = Hv.v[1];
        *(uint4*)(Wtl + ob)     = Lv.v[0];
        *(uint4*)(Wtl + ob + 8) = Lv.v[1];
    }
}

// ---------------- stage 1: proj v2 ----------------
// grid (MM/128, HH), block 256 (4 waves). Wave w owns rows w*32..+31.
// A: direct global uint4 loads from pre-split Xh/Xl (4 lanes/row = 64B line).
// W: global_load_lds into LDS [64n][64k], phys group p = g ^ (n&7) via
//    pre-swizzled per-lane source address (linear LDS dest).
__global__ __launch_bounds__(256, 4) void proj_v2_kernel(
    const u16* __restrict__ Xh, const u16* __restrict__ Xl,
    const u16* __restrict__ Wth, const u16* __restrict__ Wtl,
    u16* __restrict__ out, int z)
{
    const int h  = blockIdx.y;
    const int m0 = blockIdx.x * 128;

    __shared__ __align__(16) u16 WH[64 * 64];
    __shared__ __align__(16) u16 WL[64 * 64];

    const int tid  = threadIdx.x;
    const int lane = tid & 63, wave = tid >> 6;
    const int quad = lane >> 4, ln = lane & 15;

    // W staging: inst j covers n-rows wave*16 + j*8 .. +7; lane l -> row +l>>3,
    // phys group l&7 holds logical group (l&7)^(l>>3).
    const int lr = lane >> 3, lg = (lane & 7) ^ (lane >> 3);
    const size_t wsrc0 = ((size_t)((z * HH + h) * DKK) + wave * 16 + lr) * DD + lg * 8;
    // A direct-load base: row m0 + wave*32 + ln, k offset quad*8
    const size_t arow = (size_t)(m0 + wave * 32 + ln) * DD + quad * 8;

    f32x4 acc[2][4];
    #pragma unroll
    for (int mh = 0; mh < 2; mh++)
        #pragma unroll
        for (int nt = 0; nt < 4; nt++)
            acc[mh][nt] = (f32x4){0.f, 0.f, 0.f, 0.f};

    for (int kbase = 0; kbase < DD; kbase += 64) {
        __syncthreads();
        // A-frags: direct global loads (this chunk)
        f16x8 a_h[2][2], a_l[2][2]; // [kh][mh]
        #pragma unroll
        for (int kh = 0; kh < 2; kh++)
            #pragma unroll
            for (int mh = 0; mh < 2; mh++) {
                size_t o = arow + (size_t)(mh * 16) * DD + kbase + kh * 32;
                a_h[kh][mh] = __builtin_bit_cast(f16x8, *(const uint4*)(Xh + o));
                a_l[kh][mh] = __builtin_bit_cast(f16x8, *(const uint4*)(Xl + o));
            }
        // W tile -> LDS (async DMA, linear dest, pre-swizzled source)
        #pragma unroll
        for (int j = 0; j < 2; j++) {
            gld16(Wth + wsrc0 + (size_t)j * 8 * DD + kbase, &WH[(wave * 16 + j * 8) * 64]);
            gld16(Wtl + wsrc0 + (size_t)j * 8 * DD + kbase, &WL[(wave * 16 + j * 8) * 64]);
        }
        asm volatile("s_waitcnt vmcnt(0)" ::: "memory");
        __syncthreads();

        #pragma unroll
        for (int kh = 0; kh < 2; kh++) {
            const int kg = ((kh * 4 + quad) ^ (ln & 7)) * 8; // swizzled read
            #pragma unroll
            for (int nt = 0; nt < 4; nt++) {
                const int n = nt * 16 + ln;
                f16x8 bh = __builtin_bit_cast(f16x8, *(const uint4*)&WH[n * 64 + kg]);
                f16x8 bl = __builtin_bit_cast(f16x8, *(const uint4*)&WL[n * 64 + kg]);
                #pragma unroll
                for (int mh = 0; mh < 2; mh++) {
                    acc[mh][nt] = __builtin_amdgcn_mfma_f32_16x16x32_f16(a_l[kh][mh], bh, acc[mh][nt], 0, 0, 0);
                    acc[mh][nt] = __builtin_amdgcn_mfma_f32_16x16x32_f16(a_h[kh][mh], bl, acc[mh][nt], 0, 0, 0);
                    acc[mh][nt] = __builtin_amdgcn_mfma_f32_16x16x32_f16(a_h[kh][mh], bh, acc[mh][nt], 0, 0, 0);
                }
            }
        }
    }

    // ---- epilogue: fp16 store to [B,H,S,DK] ----
    #pragma unroll
    for (int mh = 0; mh < 2; mh++)
        #pragma unroll
        for (int r = 0; r < 4; r++) {
            int m = m0 + wave * 32 + mh * 16 + quad * 4 + r;
            int b = m >> 11, s = m & 2047;
            u16* op = out + (((size_t)(b * HH + h) * SS + s)) * DKK;
            #pragma unroll
            for (int nt = 0; nt < 4; nt++)
                op[nt * 16 + ln] = f2h(acc[mh][nt][r]);
        }
}

// ---------------- stage 2: fp16 MFMA flash attention ----------------
// unchanged core; epilogue writes cat as fp16 hi/lo (bit-identical to the
// previous fp32-store + in-kernel split in outproj).
__global__ __launch_bounds__(256) void attn_kernel(
    const u16* __restrict__ qb, const u16* __restrict__ kb,
    const u16* __restrict__ vb, u16* __restrict__ cath, u16* __restrict__ catl)
{
    __shared__ __align__(16) u16 Kt[64 * 72];
    __shared__ __align__(16) u16 Vt[64 * 72];
    __shared__ __align__(16) u16 Pw[4][16 * 72];

    const int tid  = threadIdx.x;
    const int lane = tid & 63, wave = tid >> 6;
    const int quad = lane >> 4, ln = lane & 15;
    const int xt = (SS / 64 - 1) - blockIdx.x; // heavy tiles first
    const int bh = blockIdx.y;
    const int qbase = xt * 64;

    const u16* qp = qb + ((size_t)bh * SS + qbase + wave * 16 + ln) * DKK;
    f16x8 qf0 = __builtin_bit_cast(f16x8, *(const uint4*)(qp + quad * 8));
    f16x8 qf1 = __builtin_bit_cast(f16x8, *(const uint4*)(qp + 32 + quad * 8));

    f32x4 acc[4];
    #pragma unroll
    for (int n = 0; n < 4; n++) acc[n] = (f32x4){0.f, 0.f, 0.f, 0.f};
    float mrow[4], lrow[4];
    #pragma unroll
    for (int r = 0; r < 4; r++) { mrow[r] = -INFINITY; lrow[r] = 0.f; }

    const int skey = tid >> 2, sseg = (tid & 3) * 16;
    const int vkey = tid & 63, vdkb = (tid >> 6) * 16;

    for (int kt = 0; kt <= xt; ++kt) {
        __syncthreads();
        {
            const u16* ksrc = kb + ((size_t)bh * SS + kt * 64 + skey) * DKK + sseg;
            uint4 a = *(const uint4*)ksrc;
            uint4 b = *(const uint4*)(ksrc + 8);
            *(uint4*)&Kt[skey * 72 + sseg] = a;
            *(uint4*)&Kt[skey * 72 + sseg + 8] = b;

            const u16* vsrc = vb + ((size_t)bh * SS + kt * 64 + vkey) * DKK + vdkb;
            u16 vv[16];
            *(uint4*)&vv[0] = *(const uint4*)vsrc;
            *(uint4*)&vv[8] = *(const uint4*)(vsrc + 8);
            #pragma unroll
            for (int i = 0; i < 16; i++)
                Vt[(vdkb + i) * 72 + vkey] = vv[i];
        }
        __syncthreads();

        f32x4 sa[4];
        #pragma unroll
        for (int n = 0; n < 4; n++) {
            sa[n] = (f32x4){0.f, 0.f, 0.f, 0.f};
            f16x8 kf0 = __builtin_bit_cast(f16x8,
                *(const uint4*)&Kt[(n * 16 + ln) * 72 + quad * 8]);
            sa[n] = __builtin_amdgcn_mfma_f32_16x16x32_f16(qf0, kf0, sa[n], 0, 0, 0);
            f16x8 kf1 = __builtin_bit_cast(f16x8,
                *(const uint4*)&Kt[(n * 16 + ln) * 72 + 32 + quad * 8]);
            sa[n] = __builtin_amdgcn_mfma_f32_16x16x32_f16(qf1, kf1, sa[n], 0, 0, 0);
        }

        float sc[4][4];
        const bool diag = (kt == xt);
        #pragma unroll
        for (int n = 0; n < 4; n++)
            #pragma unroll
            for (int r = 0; r < 4; r++) {
                float s = sa[n][r] * 8.0f;
                if (diag && (n * 16 + ln) > (wave * 16 + quad * 4 + r))
                    s = -INFINITY;
                sc[n][r] = s;
            }

        float rmax[4];
        #pragma unroll
        for (int r = 0; r < 4; r++)
            rmax[r] = fmaxf(fmaxf(sc[0][r], sc[1][r]), fmaxf(sc[2][r], sc[3][r]));
        #pragma unroll
        for (int off = 1; off < 16; off <<= 1)
            #pragma unroll
            for (int r = 0; r < 4; r++)
                rmax[r] = fmaxf(rmax[r], __shfl_xor(rmax[r], off));
        float alpha[4];
        #pragma unroll
        for (int r = 0; r < 4; r++) {
            float mn = fmaxf(mrow[r], rmax[r]);
            alpha[r] = __expf(mrow[r] - mn);
            mrow[r] = mn;
        }
        u16* pw = Pw[wave];
        float lsum[4] = {0.f, 0.f, 0.f, 0.f};
        #pragma unroll
        for (int n = 0; n < 4; n++)
            #pragma unroll
            for (int r = 0; r < 4; r++) {
                float p = __expf(sc[n][r] - mrow[r]);
                _Float16 ph = (_Float16)p;
                pw[(quad * 4 + r) * 72 + n * 16 + ln] = __builtin_bit_cast(u16, ph);
                lsum[r] += (float)ph;
            }
        #pragma unroll
        for (int off = 1; off < 16; off <<= 1)
            #pragma unroll
            for (int r = 0; r < 4; r++)
                lsum[r] += __shfl_xor(lsum[r], off);
        #pragma unroll
        for (int r = 0; r < 4; r++)
            lrow[r] = lrow[r] * alpha[r] + lsum[r];
        #pragma unroll
        for (int n = 0; n < 4; n++)
            #pragma unroll
            for (int r = 0; r < 4; r++)
                acc[n][r] *= alpha[r];

        asm volatile("s_waitcnt lgkmcnt(0)" ::: "memory"); // wave-local RAW
        f16x8 pf0 = __builtin_bit_cast(f16x8, *(const uint4*)&pw[ln * 72 + quad * 8]);
        f16x8 pf1 = __builtin_bit_cast(f16x8, *(const uint4*)&pw[ln * 72 + 32 + quad * 8]);

        #pragma unroll
        for (int n = 0; n < 4; n++) {
            f16x8 vf0 = __builtin_bit_cast(f16x8,
                *(const uint4*)&Vt[(n * 16 + ln) * 72 + quad * 8]);
            acc[n] = __builtin_amdgcn_mfma_f32_16x16x32_f16(pf0, vf0, acc[n], 0, 0, 0);
            f16x8 vf1 = __builtin_bit_cast(f16x8,
                *(const uint4*)&Vt[(n * 16 + ln) * 72 + 32 + quad * 8]);
            acc[n] = __builtin_amdgcn_mfma_f32_16x16x32_f16(pf1, vf1, acc[n], 0, 0, 0);
        }
    }

    const int b = bh >> 4, h = bh & 15;
    #pragma unroll
    for (int r = 0; r < 4; r++) {
        float inv = 1.0f / lrow[r];
        int row = qbase + wave * 16 + quad * 4 + r;
        size_t o = ((size_t)b * SS + row) * DD + h * DKK;
        #pragma unroll
        for (int n = 0; n < 4; n++) {
            float v = acc[n][r] * inv;
            u16 hh, ll;
            split1(v, hh, ll);
            cath[o + n * 16 + ln] = hh;
            catl[o + n * 16 + ln] = ll;
        }
    }
}

// ---------------- stage 3: outproj v2 ----------------
// out[m][n] = sum_k cat[m][k]*Wo[n][k] + bo[n]. Same structure as proj_v2;
// Wo pre-split elementwise (already [n][k] row-major = B-frag layout).
__global__ __launch_bounds__(256, 4) void outproj_v2_kernel(
    const u16* __restrict__ Ah, const u16* __restrict__ Al,
    const u16* __restrict__ Woh, const u16* __restrict__ Wol,
    const void* __restrict__ bo, const int* __restrict__ flags,
    float* __restrict__ out)
{
    const int n0 = blockIdx.y * 64;
    const int m0 = blockIdx.x * 128;

    __shared__ __align__(16) u16 WH[64 * 64];
    __shared__ __align__(16) u16 WL[64 * 64];

    const int tid  = threadIdx.x;
    const int lane = tid & 63, wave = tid >> 6;
    const int quad = lane >> 4, ln = lane & 15;

    const int lr = lane >> 3, lg = (lane & 7) ^ (lane >> 3);
    const size_t wsrc0 = ((size_t)(n0 + wave * 16 + lr)) * DD + lg * 8;
    const size_t arow  = (size_t)(m0 + wave * 32 + ln) * DD + quad * 8;

    f32x4 acc[2][4];
    #pragma unroll
    for (int mh = 0; mh < 2; mh++)
        #pragma unroll
        for (int nt = 0; nt < 4; nt++)
            acc[mh][nt] = (f32x4){0.f, 0.f, 0.f, 0.f};

    for (int kbase = 0; kbase < DD; kbase += 64) {
        __syncthreads();
        f16x8 a_h[2][2], a_l[2][2];
        #pragma unroll
        for (int kh = 0; kh < 2; kh++)
            #pragma unroll
            for (int mh = 0; mh < 2; mh++) {
                size_t o = arow + (size_t)(mh * 16) * DD + kbase + kh * 32;
                a_h[kh][mh] = __builtin_bit_cast(f16x8, *(const uint4*)(Ah + o));
                a_l[kh][mh] = __builtin_bit_cast(f16x8, *(const uint4*)(Al + o));
            }
        #pragma unroll
        for (int j = 0; j < 2; j++) {
            gld16(Woh + wsrc0 + (size_t)j * 8 * DD + kbase, &WH[(wave * 16 + j * 8) * 64]);
            gld16(Wol + wsrc0 + (size_t)j * 8 * DD + kbase, &WL[(wave * 16 + j * 8) * 64]);
        }
        asm volatile("s_waitcnt vmcnt(0)" ::: "memory");
        __syncthreads();

        #pragma unroll
        for (int kh = 0; kh < 2; kh++) {
            const int kg = ((kh * 4 + quad) ^ (ln & 7)) * 8;
            #pragma unroll
            for (int nt = 0; nt < 4; nt++) {
                const int n = nt * 16 + ln;
                f16x8 bh = __builtin_bit_cast(f16x8, *(const uint4*)&WH[n * 64 + kg]);
                f16x8 bl = __builtin_bit_cast(f16x8, *(const uint4*)&WL[n * 64 + kg]);
                #pragma unroll
                for (int mh = 0; mh < 2; mh++) {
                    acc[mh][nt] = __builtin_amdgcn_mfma_f32_16x16x32_f16(a_l[kh][mh], bh, acc[mh][nt], 0, 0, 0);
                    acc[mh][nt] = __builtin_amdgcn_mfma_f32_16x16x32_f16(a_h[kh][mh], bl, acc[mh][nt], 0, 0, 0);
                    acc[mh][nt] = __builtin_amdgcn_mfma_f32_16x16x32_f16(a_h[kh][mh], bh, acc[mh][nt], 0, 0, 0);
                }
            }
        }
    }

    // ---- epilogue: bias add + fp32 store ----
    const int bf = flags[7];
    float bias[4];
    #pragma unroll
    for (int nt = 0; nt < 4; nt++) {
        int n = n0 + nt * 16 + ln;
        bias[nt] = bf ? ((const float*)bo)[n] : bf2f(((const u16*)bo)[n]);
    }
    #pragma unroll
    for (int mh = 0; mh < 2; mh++)
        #pragma unroll
        for (int r = 0; r < 4; r++) {
            int m = m0 + wave * 32 + mh * 16 + quad * 4 + r;
            float* op = out + (size_t)m * DD + n0;
            #pragma unroll
            for (int nt = 0; nt < 4; nt++)
                op[nt * 16 + ln] = acc[mh][nt][r] + bias[nt];
        }
}

extern "C" void kernel_launch(void* const* d_in, const int* in_sizes, int n_in,
                              void* d_out, int out_size, void* d_ws, size_t ws_size,
                              hipStream_t stream)
{
    const void* Q = d_in[0];
    const void* K = d_in[1];
    const void* V = d_in[2];
    const int widx = (n_in >= 9) ? 4 : 3; // mask present iff n_in >= 9 (ignored)
    const void* Wq = d_in[widx + 0];
    const void* Wk = d_in[widx + 1];
    const void* Wv = d_in[widx + 2];
    const void* Wo = d_in[widx + 3];
    const void* bo = d_in[widx + 4];
    float* out = (float*)d_out;

    const size_t per = (size_t)BB * HH * SS * DKK; // 8,388,608 elements
    u16* qb = (u16*)d_ws;
    u16* kb = qb + per;
    u16* vb = kb + per;
    u16* xc = vb + per;          // 2*per region, dual-purpose:
    u16* Xh = xc;                //   during proj: X hi/lo
    u16* Xl = xc + per;
    u16* cath = xc;              //   after proj: cat hi/lo (attn output)
    u16* catl = xc + per;
    const size_t wtn = (size_t)3 * HH * DKK * DD; // 3,145,728
    u16* Wth = xc + 2 * per;
    u16* Wtl = Wth + wtn;
    u16* Woh = Wtl + wtn;
    u16* Wol = Woh + (size_t)DD * DD;
    int* flags = (int*)(Wol + (size_t)DD * DD);
    // total ws: ~100.7 MB

    sniff_kernel<<<8, 64, 0, stream>>>(
        (const u16*)Q, (const u16*)K, (const u16*)V,
        (const u16*)Wq, (const u16*)Wk, (const u16*)Wv,
        (const u16*)Wo, (const u16*)bo, flags);

    split_wqkv_kernel<<<dim3(DD / 64, HH, 3), 256, 0, stream>>>(
        Wq, Wk, Wv, flags, Wth, Wtl);
    split_x_kernel<<<(DD * DD) / 2048, 256, 0, stream>>>(Wo, flags, 6, Woh, Wol);

    dim3 gp(MM / 128, HH);
    split_x_kernel<<<(MM * DD) / 2048, 256, 0, stream>>>(Q, flags, 0, Xh, Xl);
    proj_v2_kernel<<<gp, 256, 0, stream>>>(Xh, Xl, Wth, Wtl, qb, 0);
    split_x_kernel<<<(MM * DD) / 2048, 256, 0, stream>>>(K, flags, 1, Xh, Xl);
    proj_v2_kernel<<<gp, 256, 0, stream>>>(Xh, Xl, Wth, Wtl, kb, 1);
    split_x_kernel<<<(MM * DD) / 2048, 256, 0, stream>>>(V, flags, 2, Xh, Xl);
    proj_v2_kernel<<<gp, 256, 0, stream>>>(Xh, Xl, Wth, Wtl, vb, 2);

    attn_kernel<<<dim3(SS / 64, BB * HH), 256, 0, stream>>>(qb, kb, vb, cath, catl);

    outproj_v2_kernel<<<dim3(MM / 128, DD / 64), 256, 0, stream>>>(
        cath, catl, Woh, Wol, bo, flags, out);
}

// Round 3
// 647.290 us; speedup vs baseline: 1.6165x; 1.1728x over previous
//
#include <hip/hip_runtime.h>
#include <math.h>

// MultiHeadAttention: B=4,S=2048,D=1024,H=16,DK=64
// Round 9: attention restructured — QBLK=128, 8 waves/block (512 thr),
//   register prefetch of next K/V tile (async-stage), XCD-affinity block
//   mapping (bh ≡ blockIdx mod 8 -> per-XCD L2-resident K/V), heavy-first.
//   Per-wave math identical to verified round-8 kernel.
//   stage 1: proj_v2 (unchanged)  stage 3: outproj_v2 (unchanged)

#define BB 4
#define SS 2048
#define DD 1024
#define HH 16
#define DKK 64
#define MM (BB * SS) // 8192

typedef unsigned short u16;
typedef _Float16 f16x8 __attribute__((ext_vector_type(8)));
typedef float f32x4 __attribute__((ext_vector_type(4)));
typedef __attribute__((address_space(1))) unsigned int gas_u32;
typedef __attribute__((address_space(3))) unsigned int las_u32;

__device__ __forceinline__ float bf2f(u16 u) {
    union { unsigned int i; float f; } c;
    c.i = ((unsigned int)u) << 16;
    return c.f;
}
__device__ __forceinline__ u16 f2h(float f) {
    _Float16 h = (_Float16)f; // RNE
    return __builtin_bit_cast(u16, h);
}
__device__ __forceinline__ void split1(float x, u16& hi, u16& lo) {
    _Float16 hh = (_Float16)x;
    hi = __builtin_bit_cast(u16, hh);
    lo = f2h(x - (float)hh);
}
// global(16B/lane) -> LDS at wave-uniform base + lane*16
__device__ __forceinline__ void gld16(const void* g, void* l) {
    __builtin_amdgcn_global_load_lds((gas_u32*)g, (las_u32*)l, 16, 0, 0);
}

// ---------------- stage 0: dtype sniffer (insurance) ----------------
__global__ void sniff_kernel(const u16* t0, const u16* t1, const u16* t2,
                             const u16* t3, const u16* t4, const u16* t5,
                             const u16* t6, const u16* t7, int* flags)
{
    const u16* ptrs[8] = {t0, t1, t2, t3, t4, t5, t6, t7};
    const u16* p = ptrs[blockIdx.x];
    int tid = threadIdx.x; // 64
    int cnt = 0;
    #pragma unroll
    for (int i = 0; i < 8; i++) {
        u16 v = p[tid * 8 + i];
        int e = (v >> 7) & 0xFF;
        if (e >= 0xF0 || (e <= 0x0F && (v & 0x7FFF) != 0)) cnt++;
    }
    #pragma unroll
    for (int off = 32; off; off >>= 1) cnt += __shfl_down(cnt, off);
    if (tid == 0) flags[blockIdx.x] = (cnt >= 4) ? 1 : 0;
}

// ---------------- stage 0.5a: elementwise hi/lo split (X and Wo) ----------------
__global__ __launch_bounds__(256) void split_x_kernel(
    const void* __restrict__ X, const int* __restrict__ flags, int fidx,
    u16* __restrict__ Xh, u16* __restrict__ Xl)
{
    const int xf = flags[fidx];
    size_t idx = ((size_t)blockIdx.x * 256 + threadIdx.x) * 8;
    float x[8];
    if (xf) {
        float4 a = *(const float4*)((const float*)X + idx);
        float4 b = *(const float4*)((const float*)X + idx + 4);
        x[0] = a.x; x[1] = a.y; x[2] = a.z; x[3] = a.w;
        x[4] = b.x; x[5] = b.y; x[6] = b.z; x[7] = b.w;
    } else {
        ushort4 a = *(const ushort4*)((const u16*)X + idx);
        ushort4 b = *(const ushort4*)((const u16*)X + idx + 4);
        x[0] = bf2f(a.x); x[1] = bf2f(a.y); x[2] = bf2f(a.z); x[3] = bf2f(a.w);
        x[4] = bf2f(b.x); x[5] = bf2f(b.y); x[6] = bf2f(b.z); x[7] = bf2f(b.w);
    }
    union { u16 u[8]; uint4 v; } H, L;
    #pragma unroll
    for (int i = 0; i < 8; i++) split1(x[i], H.u[i], L.u[i]);
    *(uint4*)(Xh + idx) = H.v;
    *(uint4*)(Xl + idx) = L.v;
}

// ---------------- stage 0.5b: Wq/Wk/Wv transpose + split ----------------
__global__ __launch_bounds__(256) void split_wqkv_kernel(
    const void* __restrict__ Wq, const void* __restrict__ Wk, const void* __restrict__ Wv,
    const int* __restrict__ flags, u16* __restrict__ Wth, u16* __restrict__ Wtl)
{
    const int z = blockIdx.z, h = blockIdx.y, kc = blockIdx.x;
    const void* __restrict__ W = (z == 0) ? Wq : (z == 1) ? Wk : Wv;
    const int wf = flags[3 + z];
    __shared__ float T[64][65];
    const int t = threadIdx.x;
    {
        const int kk = t >> 2, ns = (t & 3) * 16;
        const size_t base = (size_t)h * DD * DKK + (size_t)(kc * 64 + kk) * DKK + ns;
        #pragma unroll
        for (int j = 0; j < 4; j++) {
            if (wf) {
                float4 v = *(const float4*)((const float*)W + base + 4 * j);
                T[kk][ns + 4 * j + 0] = v.x; T[kk][ns + 4 * j + 1] = v.y;
                T[kk][ns + 4 * j + 2] = v.z; T[kk][ns + 4 * j + 3] = v.w;
            } else {
                ushort4 v = *(const ushort4*)((const u16*)W + base + 4 * j);
                T[kk][ns + 4 * j + 0] = bf2f(v.x); T[kk][ns + 4 * j + 1] = bf2f(v.y);
                T[kk][ns + 4 * j + 2] = bf2f(v.z); T[kk][ns + 4 * j + 3] = bf2f(v.w);
            }
        }
    }
    __syncthreads();
    {
        const int n = t >> 2, ks = (t & 3) * 16;
        union { u16 u[16]; uint4 v[2]; } Hv, Lv;
        #pragma unroll
        for (int i = 0; i < 16; i++) split1(T[ks + i][n], Hv.u[i], Lv.u[i]);
        size_t ob = ((size_t)(z * HH + h) * DKK + n) * DD + kc * 64 + ks;
        *(uint4*)(Wth + ob)     = Hv.v[0];
        *(uint4*)(Wth + ob + 8) = Hv.v[1];
        *(uint4*)(Wtl + ob)     = Lv.v[0];
        *(uint4*)(Wtl + ob + 8) = Lv.v[1];
    }
}

// ---------------- stage 1: proj v2 (unchanged) ----------------
__global__ __launch_bounds__(256, 4) void proj_v2_kernel(
    const u16* __restrict__ Xh, const u16* __restrict__ Xl,
    const u16* __restrict__ Wth, const u16* __restrict__ Wtl,
    u16* __restrict__ out, int z)
{
    const int h  = blockIdx.y;
    const int m0 = blockIdx.x * 128;

    __shared__ __align__(16) u16 WH[64 * 64];
    __shared__ __align__(16) u16 WL[64 * 64];

    const int tid  = threadIdx.x;
    const int lane = tid & 63, wave = tid >> 6;
    const int quad = lane >> 4, ln = lane & 15;

    const int lr = lane >> 3, lg = (lane & 7) ^ (lane >> 3);
    const size_t wsrc0 = ((size_t)((z * HH + h) * DKK) + wave * 16 + lr) * DD + lg * 8;
    const size_t arow = (size_t)(m0 + wave * 32 + ln) * DD + quad * 8;

    f32x4 acc[2][4];
    #pragma unroll
    for (int mh = 0; mh < 2; mh++)
        #pragma unroll
        for (int nt = 0; nt < 4; nt++)
            acc[mh][nt] = (f32x4){0.f, 0.f, 0.f, 0.f};

    for (int kbase = 0; kbase < DD; kbase += 64) {
        __syncthreads();
        f16x8 a_h[2][2], a_l[2][2]; // [kh][mh]
        #pragma unroll
        for (int kh = 0; kh < 2; kh++)
            #pragma unroll
            for (int mh = 0; mh < 2; mh++) {
                size_t o = arow + (size_t)(mh * 16) * DD + kbase + kh * 32;
                a_h[kh][mh] = __builtin_bit_cast(f16x8, *(const uint4*)(Xh + o));
                a_l[kh][mh] = __builtin_bit_cast(f16x8, *(const uint4*)(Xl + o));
            }
        #pragma unroll
        for (int j = 0; j < 2; j++) {
            gld16(Wth + wsrc0 + (size_t)j * 8 * DD + kbase, &WH[(wave * 16 + j * 8) * 64]);
            gld16(Wtl + wsrc0 + (size_t)j * 8 * DD + kbase, &WL[(wave * 16 + j * 8) * 64]);
        }
        asm volatile("s_waitcnt vmcnt(0)" ::: "memory");
        __syncthreads();

        #pragma unroll
        for (int kh = 0; kh < 2; kh++) {
            const int kg = ((kh * 4 + quad) ^ (ln & 7)) * 8; // swizzled read
            #pragma unroll
            for (int nt = 0; nt < 4; nt++) {
                const int n = nt * 16 + ln;
                f16x8 bh = __builtin_bit_cast(f16x8, *(const uint4*)&WH[n * 64 + kg]);
                f16x8 bl = __builtin_bit_cast(f16x8, *(const uint4*)&WL[n * 64 + kg]);
                #pragma unroll
                for (int mh = 0; mh < 2; mh++) {
                    acc[mh][nt] = __builtin_amdgcn_mfma_f32_16x16x32_f16(a_l[kh][mh], bh, acc[mh][nt], 0, 0, 0);
                    acc[mh][nt] = __builtin_amdgcn_mfma_f32_16x16x32_f16(a_h[kh][mh], bl, acc[mh][nt], 0, 0, 0);
                    acc[mh][nt] = __builtin_amdgcn_mfma_f32_16x16x32_f16(a_h[kh][mh], bh, acc[mh][nt], 0, 0, 0);
                }
            }
        }
    }

    #pragma unroll
    for (int mh = 0; mh < 2; mh++)
        #pragma unroll
        for (int r = 0; r < 4; r++) {
            int m = m0 + wave * 32 + mh * 16 + quad * 4 + r;
            int b = m >> 11, s = m & 2047;
            u16* op = out + (((size_t)(b * HH + h) * SS + s)) * DKK;
            #pragma unroll
            for (int nt = 0; nt < 4; nt++)
                op[nt * 16 + ln] = f2h(acc[mh][nt][r]);
        }
}

// ---------------- stage 2: fp16 MFMA flash attention v3 ----------------
// 1024 blocks x 512 threads (8 waves). Block p: bh = (p>>3 >>4)*8 + (p&7)
// (XCD-affinity: all 16 q-blocks of bh land on XCD bh%8), xt = 15-heavy-first.
// Block covers q rows [xt*128, xt*128+128); wave w owns rows +w*16..+15.
// K/V tiles of 64 keys; register prefetch of tile kt+1 while computing kt.
__global__ __launch_bounds__(512) void attn_kernel(
    const u16* __restrict__ qb, const u16* __restrict__ kb,
    const u16* __restrict__ vb, u16* __restrict__ cath, u16* __restrict__ catl)
{
    __shared__ __align__(16) u16 Kt[64 * 72];
    __shared__ __align__(16) u16 Vt[64 * 72];
    __shared__ __align__(16) u16 Pw[8][16 * 72];

    const int tid  = threadIdx.x;
    const int lane = tid & 63, wave = tid >> 6; // 8 waves
    const int quad = lane >> 4, ln = lane & 15;

    const int p  = blockIdx.x;
    const int bh = ((p >> 3) >> 4) * 8 + (p & 7);
    const int xt = 15 - ((p >> 3) & 15); // heavy tiles first
    const int qbase = xt * 128;
    const int ktmax = 2 * xt + 1;

    const int wq = qbase + wave * 16;  // wave's first q row
    const int diagkt = wq >> 6;        // kv tile containing this wave's diagonal
    const int wqmax = wq + 15;

    const u16* qp = qb + ((size_t)bh * SS + wq + ln) * DKK;
    f16x8 qf0 = __builtin_bit_cast(f16x8, *(const uint4*)(qp + quad * 8));
    f16x8 qf1 = __builtin_bit_cast(f16x8, *(const uint4*)(qp + 32 + quad * 8));

    f32x4 acc[4];
    #pragma unroll
    for (int n = 0; n < 4; n++) acc[n] = (f32x4){0.f, 0.f, 0.f, 0.f};
    float mrow[4], lrow[4];
    #pragma unroll
    for (int r = 0; r < 4; r++) { mrow[r] = -INFINITY; lrow[r] = 0.f; }

    // staging maps (512 threads): K 1x uint4/thread, V 8 u16/thread (transpose)
    const int skey = tid >> 3, sseg = (tid & 7) * 8;
    const int vkey = tid & 63, vdkb = (tid >> 6) * 8;

    const u16* kbp = kb + (size_t)bh * SS * DKK;
    const u16* vbp = vb + (size_t)bh * SS * DKK;

    // prologue: stage tile 0
    {
        uint4 ka = *(const uint4*)(kbp + (size_t)skey * DKK + sseg);
        uint4 va = *(const uint4*)(vbp + (size_t)vkey * DKK + vdkb);
        *(uint4*)&Kt[skey * 72 + sseg] = ka;
        u16 vv[8];
        *(uint4*)&vv[0] = va;
        #pragma unroll
        for (int i = 0; i < 8; i++)
            Vt[(vdkb + i) * 72 + vkey] = vv[i];
    }
    __syncthreads();

    for (int kt = 0; kt <= ktmax; ++kt) {
        // prefetch next tile into registers (global latency hides under compute)
        uint4 ka, va;
        const bool pf = (kt < ktmax);
        if (pf) {
            ka = *(const uint4*)(kbp + (size_t)((kt + 1) * 64 + skey) * DKK + sseg);
            va = *(const uint4*)(vbp + (size_t)((kt + 1) * 64 + vkey) * DKK + vdkb);
        }

        if (kt * 64 <= wqmax) { // wave has unmasked keys in this tile
            f32x4 sa[4];
            #pragma unroll
            for (int n = 0; n < 4; n++) {
                sa[n] = (f32x4){0.f, 0.f, 0.f, 0.f};
                f16x8 kf0 = __builtin_bit_cast(f16x8,
                    *(const uint4*)&Kt[(n * 16 + ln) * 72 + quad * 8]);
                sa[n] = __builtin_amdgcn_mfma_f32_16x16x32_f16(qf0, kf0, sa[n], 0, 0, 0);
                f16x8 kf1 = __builtin_bit_cast(f16x8,
                    *(const uint4*)&Kt[(n * 16 + ln) * 72 + 32 + quad * 8]);
                sa[n] = __builtin_amdgcn_mfma_f32_16x16x32_f16(qf1, kf1, sa[n], 0, 0, 0);
            }

            float sc[4][4];
            const bool diag = (kt == diagkt);
            #pragma unroll
            for (int n = 0; n < 4; n++)
                #pragma unroll
                for (int r = 0; r < 4; r++) {
                    float s = sa[n][r] * 8.0f;
                    if (diag && (kt * 64 + n * 16 + ln) > (wq + quad * 4 + r))
                        s = -INFINITY;
                    sc[n][r] = s;
                }

            float rmax[4];
            #pragma unroll
            for (int r = 0; r < 4; r++)
                rmax[r] = fmaxf(fmaxf(sc[0][r], sc[1][r]), fmaxf(sc[2][r], sc[3][r]));
            #pragma unroll
            for (int off = 1; off < 16; off <<= 1)
                #pragma unroll
                for (int r = 0; r < 4; r++)
                    rmax[r] = fmaxf(rmax[r], __shfl_xor(rmax[r], off));
            float alpha[4];
            #pragma unroll
            for (int r = 0; r < 4; r++) {
                float mn = fmaxf(mrow[r], rmax[r]);
                alpha[r] = __expf(mrow[r] - mn);
                mrow[r] = mn;
            }
            u16* pw = Pw[wave];
            float lsum[4] = {0.f, 0.f, 0.f, 0.f};
            #pragma unroll
            for (int n = 0; n < 4; n++)
                #pragma unroll
                for (int r = 0; r < 4; r++) {
                    float pp = __expf(sc[n][r] - mrow[r]);
                    _Float16 ph = (_Float16)pp;
                    pw[(quad * 4 + r) * 72 + n * 16 + ln] = __builtin_bit_cast(u16, ph);
                    lsum[r] += (float)ph;
                }
            #pragma unroll
            for (int off = 1; off < 16; off <<= 1)
                #pragma unroll
                for (int r = 0; r < 4; r++)
                    lsum[r] += __shfl_xor(lsum[r], off);
            #pragma unroll
            for (int r = 0; r < 4; r++)
                lrow[r] = lrow[r] * alpha[r] + lsum[r];
            #pragma unroll
            for (int n = 0; n < 4; n++)
                #pragma unroll
                for (int r = 0; r < 4; r++)
                    acc[n][r] *= alpha[r];

            asm volatile("s_waitcnt lgkmcnt(0)" ::: "memory"); // wave-local RAW
            f16x8 pf0 = __builtin_bit_cast(f16x8, *(const uint4*)&pw[ln * 72 + quad * 8]);
            f16x8 pf1 = __builtin_bit_cast(f16x8, *(const uint4*)&pw[ln * 72 + 32 + quad * 8]);

            #pragma unroll
            for (int n = 0; n < 4; n++) {
                f16x8 vf0 = __builtin_bit_cast(f16x8,
                    *(const uint4*)&Vt[(n * 16 + ln) * 72 + quad * 8]);
                acc[n] = __builtin_amdgcn_mfma_f32_16x16x32_f16(pf0, vf0, acc[n], 0, 0, 0);
                f16x8 vf1 = __builtin_bit_cast(f16x8,
                    *(const uint4*)&Vt[(n * 16 + ln) * 72 + 32 + quad * 8]);
                acc[n] = __builtin_amdgcn_mfma_f32_16x16x32_f16(pf1, vf1, acc[n], 0, 0, 0);
            }
        }

        __syncthreads(); // all waves done reading Kt/Vt
        if (pf) {
            *(uint4*)&Kt[skey * 72 + sseg] = ka;
            u16 vv[8];
            *(uint4*)&vv[0] = va;
            #pragma unroll
            for (int i = 0; i < 8; i++)
                Vt[(vdkb + i) * 72 + vkey] = vv[i];
        }
        __syncthreads(); // next tile staged
    }

    const int b = bh >> 4, h = bh & 15;
    #pragma unroll
    for (int r = 0; r < 4; r++) {
        float inv = 1.0f / lrow[r];
        int row = wq + quad * 4 + r;
        size_t o = ((size_t)b * SS + row) * DD + h * DKK;
        #pragma unroll
        for (int n = 0; n < 4; n++) {
            float v = acc[n][r] * inv;
            u16 hh, ll;
            split1(v, hh, ll);
            cath[o + n * 16 + ln] = hh;
            catl[o + n * 16 + ln] = ll;
        }
    }
}

// ---------------- stage 3: outproj v2 (unchanged) ----------------
__global__ __launch_bounds__(256, 4) void outproj_v2_kernel(
    const u16* __restrict__ Ah, const u16* __restrict__ Al,
    const u16* __restrict__ Woh, const u16* __restrict__ Wol,
    const void* __restrict__ bo, const int* __restrict__ flags,
    float* __restrict__ out)
{
    const int n0 = blockIdx.y * 64;
    const int m0 = blockIdx.x * 128;

    __shared__ __align__(16) u16 WH[64 * 64];
    __shared__ __align__(16) u16 WL[64 * 64];

    const int tid  = threadIdx.x;
    const int lane = tid & 63, wave = tid >> 6;
    const int quad = lane >> 4, ln = lane & 15;

    const int lr = lane >> 3, lg = (lane & 7) ^ (lane >> 3);
    const size_t wsrc0 = ((size_t)(n0 + wave * 16 + lr)) * DD + lg * 8;
    const size_t arow  = (size_t)(m0 + wave * 32 + ln) * DD + quad * 8;

    f32x4 acc[2][4];
    #pragma unroll
    for (int mh = 0; mh < 2; mh++)
        #pragma unroll
        for (int nt = 0; nt < 4; nt++)
            acc[mh][nt] = (f32x4){0.f, 0.f, 0.f, 0.f};

    for (int kbase = 0; kbase < DD; kbase += 64) {
        __syncthreads();
        f16x8 a_h[2][2], a_l[2][2];
        #pragma unroll
        for (int kh = 0; kh < 2; kh++)
            #pragma unroll
            for (int mh = 0; mh < 2; mh++) {
                size_t o = arow + (size_t)(mh * 16) * DD + kbase + kh * 32;
                a_h[kh][mh] = __builtin_bit_cast(f16x8, *(const uint4*)(Ah + o));
                a_l[kh][mh] = __builtin_bit_cast(f16x8, *(const uint4*)(Al + o));
            }
        #pragma unroll
        for (int j = 0; j < 2; j++) {
            gld16(Woh + wsrc0 + (size_t)j * 8 * DD + kbase, &WH[(wave * 16 + j * 8) * 64]);
            gld16(Wol + wsrc0 + (size_t)j * 8 * DD + kbase, &WL[(wave * 16 + j * 8) * 64]);
        }
        asm volatile("s_waitcnt vmcnt(0)" ::: "memory");
        __syncthreads();

        #pragma unroll
        for (int kh = 0; kh < 2; kh++) {
            const int kg = ((kh * 4 + quad) ^ (ln & 7)) * 8;
            #pragma unroll
            for (int nt = 0; nt < 4; nt++) {
                const int n = nt * 16 + ln;
                f16x8 bh = __builtin_bit_cast(f16x8, *(const uint4*)&WH[n * 64 + kg]);
                f16x8 bl = __builtin_bit_cast(f16x8, *(const uint4*)&WL[n * 64 + kg]);
                #pragma unroll
                for (int mh = 0; mh < 2; mh++) {
                    acc[mh][nt] = __builtin_amdgcn_mfma_f32_16x16x32_f16(a_l[kh][mh], bh, acc[mh][nt], 0, 0, 0);
                    acc[mh][nt] = __builtin_amdgcn_mfma_f32_16x16x32_f16(a_h[kh][mh], bl, acc[mh][nt], 0, 0, 0);
                    acc[mh][nt] = __builtin_amdgcn_mfma_f32_16x16x32_f16(a_h[kh][mh], bh, acc[mh][nt], 0, 0, 0);
                }
            }
        }
    }

    const int bf = flags[7];
    float bias[4];
    #pragma unroll
    for (int nt = 0; nt < 4; nt++) {
        int n = n0 + nt * 16 + ln;
        bias[nt] = bf ? ((const float*)bo)[n] : bf2f(((const u16*)bo)[n]);
    }
    #pragma unroll
    for (int mh = 0; mh < 2; mh++)
        #pragma unroll
        for (int r = 0; r < 4; r++) {
            int m = m0 + wave * 32 + mh * 16 + quad * 4 + r;
            float* op = out + (size_t)m * DD + n0;
            #pragma unroll
            for (int nt = 0; nt < 4; nt++)
                op[nt * 16 + ln] = acc[mh][nt][r] + bias[nt];
        }
}

extern "C" void kernel_launch(void* const* d_in, const int* in_sizes, int n_in,
                              void* d_out, int out_size, void* d_ws, size_t ws_size,
                              hipStream_t stream)
{
    const void* Q = d_in[0];
    const void* K = d_in[1];
    const void* V = d_in[2];
    const int widx = (n_in >= 9) ? 4 : 3; // mask present iff n_in >= 9 (ignored)
    const void* Wq = d_in[widx + 0];
    const void* Wk = d_in[widx + 1];
    const void* Wv = d_in[widx + 2];
    const void* Wo = d_in[widx + 3];
    const void* bo = d_in[widx + 4];
    float* out = (float*)d_out;

    const size_t per = (size_t)BB * HH * SS * DKK; // 8,388,608 elements
    u16* qb = (u16*)d_ws;
    u16* kb = qb + per;
    u16* vb = kb + per;
    u16* xc = vb + per;          // 2*per region, dual-purpose:
    u16* Xh = xc;                //   during proj: X hi/lo
    u16* Xl = xc + per;
    u16* cath = xc;              //   after proj: cat hi/lo (attn output)
    u16* catl = xc + per;
    const size_t wtn = (size_t)3 * HH * DKK * DD; // 3,145,728
    u16* Wth = xc + 2 * per;
    u16* Wtl = Wth + wtn;
    u16* Woh = Wtl + wtn;
    u16* Wol = Woh + (size_t)DD * DD;
    int* flags = (int*)(Wol + (size_t)DD * DD);

    sniff_kernel<<<8, 64, 0, stream>>>(
        (const u16*)Q, (const u16*)K, (const u16*)V,
        (const u16*)Wq, (const u16*)Wk, (const u16*)Wv,
        (const u16*)Wo, (const u16*)bo, flags);

    split_wqkv_kernel<<<dim3(DD / 64, HH, 3), 256, 0, stream>>>(
        Wq, Wk, Wv, flags, Wth, Wtl);
    split_x_kernel<<<(DD * DD) / 2048, 256, 0, stream>>>(Wo, flags, 6, Woh, Wol);

    dim3 gp(MM / 128, HH);
    split_x_kernel<<<(MM * DD) / 2048, 256, 0, stream>>>(Q, flags, 0, Xh, Xl);
    proj_v2_kernel<<<gp, 256, 0, stream>>>(Xh, Xl, Wth, Wtl, qb, 0);
    split_x_kernel<<<(MM * DD) / 2048, 256, 0, stream>>>(K, flags, 1, Xh, Xl);
    proj_v2_kernel<<<gp, 256, 0, stream>>>(Xh, Xl, Wth, Wtl, kb, 1);
    split_x_kernel<<<(MM * DD) / 2048, 256, 0, stream>>>(V, flags, 2, Xh, Xl);
    proj_v2_kernel<<<gp, 256, 0, stream>>>(Xh, Xl, Wth, Wtl, vb, 2);

    attn_kernel<<<(SS / 128) * BB * HH, 512, 0, stream>>>(qb, kb, vb, cath, catl);

    outproj_v2_kernel<<<dim3(MM / 128, DD / 64), 256, 0, stream>>>(
        cath, catl, Woh, Wol, bo, flags, out);
}

// Round 4
// 490.035 us; speedup vs baseline: 2.1353x; 1.3209x over previous
//
#include <hip/hip_runtime.h>
#include <math.h>

// MultiHeadAttention: B=4,S=2048,D=1024,H=16,DK=64
// Round 10:
//   attn: paired causal q-tiles (i, 15-i) per block -> constant 34 tile-iters
//         per block, 512 blocks, no tail imbalance. Per-row math identical.
//   proj/outproj: BN 64 -> 128 (2 heads per proj block). MFMA per sync
//         doubles, W traffic halves. Accumulation order bit-identical.

#define BB 4
#define SS 2048
#define DD 1024
#define HH 16
#define DKK 64
#define MM (BB * SS) // 8192

typedef unsigned short u16;
typedef _Float16 f16x8 __attribute__((ext_vector_type(8)));
typedef float f32x4 __attribute__((ext_vector_type(4)));
typedef __attribute__((address_space(1))) unsigned int gas_u32;
typedef __attribute__((address_space(3))) unsigned int las_u32;

__device__ __forceinline__ float bf2f(u16 u) {
    union { unsigned int i; float f; } c;
    c.i = ((unsigned int)u) << 16;
    return c.f;
}
__device__ __forceinline__ u16 f2h(float f) {
    _Float16 h = (_Float16)f; // RNE
    return __builtin_bit_cast(u16, h);
}
__device__ __forceinline__ void split1(float x, u16& hi, u16& lo) {
    _Float16 hh = (_Float16)x;
    hi = __builtin_bit_cast(u16, hh);
    lo = f2h(x - (float)hh);
}
// global(16B/lane) -> LDS at wave-uniform base + lane*16
__device__ __forceinline__ void gld16(const void* g, void* l) {
    __builtin_amdgcn_global_load_lds((gas_u32*)g, (las_u32*)l, 16, 0, 0);
}

// ---------------- stage 0: dtype sniffer (insurance) ----------------
__global__ void sniff_kernel(const u16* t0, const u16* t1, const u16* t2,
                             const u16* t3, const u16* t4, const u16* t5,
                             const u16* t6, const u16* t7, int* flags)
{
    const u16* ptrs[8] = {t0, t1, t2, t3, t4, t5, t6, t7};
    const u16* p = ptrs[blockIdx.x];
    int tid = threadIdx.x; // 64
    int cnt = 0;
    #pragma unroll
    for (int i = 0; i < 8; i++) {
        u16 v = p[tid * 8 + i];
        int e = (v >> 7) & 0xFF;
        if (e >= 0xF0 || (e <= 0x0F && (v & 0x7FFF) != 0)) cnt++;
    }
    #pragma unroll
    for (int off = 32; off; off >>= 1) cnt += __shfl_down(cnt, off);
    if (tid == 0) flags[blockIdx.x] = (cnt >= 4) ? 1 : 0;
}

// ---------------- stage 0.5a: elementwise hi/lo split (X and Wo) ----------------
__global__ __launch_bounds__(256) void split_x_kernel(
    const void* __restrict__ X, const int* __restrict__ flags, int fidx,
    u16* __restrict__ Xh, u16* __restrict__ Xl)
{
    const int xf = flags[fidx];
    size_t idx = ((size_t)blockIdx.x * 256 + threadIdx.x) * 8;
    float x[8];
    if (xf) {
        float4 a = *(const float4*)((const float*)X + idx);
        float4 b = *(const float4*)((const float*)X + idx + 4);
        x[0] = a.x; x[1] = a.y; x[2] = a.z; x[3] = a.w;
        x[4] = b.x; x[5] = b.y; x[6] = b.z; x[7] = b.w;
    } else {
        ushort4 a = *(const ushort4*)((const u16*)X + idx);
        ushort4 b = *(const ushort4*)((const u16*)X + idx + 4);
        x[0] = bf2f(a.x); x[1] = bf2f(a.y); x[2] = bf2f(a.z); x[3] = bf2f(a.w);
        x[4] = bf2f(b.x); x[5] = bf2f(b.y); x[6] = bf2f(b.z); x[7] = bf2f(b.w);
    }
    union { u16 u[8]; uint4 v; } H, L;
    #pragma unroll
    for (int i = 0; i < 8; i++) split1(x[i], H.u[i], L.u[i]);
    *(uint4*)(Xh + idx) = H.v;
    *(uint4*)(Xl + idx) = L.v;
}

// ---------------- stage 0.5b: Wq/Wk/Wv transpose + split ----------------
__global__ __launch_bounds__(256) void split_wqkv_kernel(
    const void* __restrict__ Wq, const void* __restrict__ Wk, const void* __restrict__ Wv,
    const int* __restrict__ flags, u16* __restrict__ Wth, u16* __restrict__ Wtl)
{
    const int z = blockIdx.z, h = blockIdx.y, kc = blockIdx.x;
    const void* __restrict__ W = (z == 0) ? Wq : (z == 1) ? Wk : Wv;
    const int wf = flags[3 + z];
    __shared__ float T[64][65];
    const int t = threadIdx.x;
    {
        const int kk = t >> 2, ns = (t & 3) * 16;
        const size_t base = (size_t)h * DD * DKK + (size_t)(kc * 64 + kk) * DKK + ns;
        #pragma unroll
        for (int j = 0; j < 4; j++) {
            if (wf) {
                float4 v = *(const float4*)((const float*)W + base + 4 * j);
                T[kk][ns + 4 * j + 0] = v.x; T[kk][ns + 4 * j + 1] = v.y;
                T[kk][ns + 4 * j + 2] = v.z; T[kk][ns + 4 * j + 3] = v.w;
            } else {
                ushort4 v = *(const ushort4*)((const u16*)W + base + 4 * j);
                T[kk][ns + 4 * j + 0] = bf2f(v.x); T[kk][ns + 4 * j + 1] = bf2f(v.y);
                T[kk][ns + 4 * j + 2] = bf2f(v.z); T[kk][ns + 4 * j + 3] = bf2f(v.w);
            }
        }
    }
    __syncthreads();
    {
        const int n = t >> 2, ks = (t & 3) * 16;
        union { u16 u[16]; uint4 v[2]; } Hv, Lv;
        #pragma unroll
        for (int i = 0; i < 16; i++) split1(T[ks + i][n], Hv.u[i], Lv.u[i]);
        size_t ob = ((size_t)(z * HH + h) * DKK + n) * DD + kc * 64 + ks;
        *(uint4*)(Wth + ob)     = Hv.v[0];
        *(uint4*)(Wth + ob + 8) = Hv.v[1];
        *(uint4*)(Wtl + ob)     = Lv.v[0];
        *(uint4*)(Wtl + ob + 8) = Lv.v[1];
    }
}

// ---------------- stage 1: proj v3 (BN=128, 2 heads/block) ----------------
// grid (MM/128, HH/2), block 256 (4 waves). Wave w: A rows w*32..+31, all 128 n.
// W rows [0,128) = heads h0,h0+1 contiguous in [z][h][n][k] layout.
__global__ __launch_bounds__(256, 4) void proj_v3_kernel(
    const u16* __restrict__ Xh, const u16* __restrict__ Xl,
    const u16* __restrict__ Wth, const u16* __restrict__ Wtl,
    u16* __restrict__ out, int z)
{
    const int h0 = blockIdx.y * 2;
    const int m0 = blockIdx.x * 128;

    __shared__ __align__(16) u16 WH[128 * 64];
    __shared__ __align__(16) u16 WL[128 * 64];

    const int tid  = threadIdx.x;
    const int lane = tid & 63, wave = tid >> 6;
    const int quad = lane >> 4, ln = lane & 15;

    // W staging: wave w rows w*32 + j*8 .. +7 (j=0..3); lane l -> row +(l>>3),
    // phys group l&7 holds logical group (l&7)^(l>>3).
    const int lr = lane >> 3, lg = (lane & 7) ^ (lane >> 3);
    const size_t wsrc0 = ((size_t)((z * HH + h0) * DKK) + wave * 32 + lr) * DD + lg * 8;
    const size_t arow = (size_t)(m0 + wave * 32 + ln) * DD + quad * 8;

    f32x4 acc[2][8];
    #pragma unroll
    for (int mh = 0; mh < 2; mh++)
        #pragma unroll
        for (int nt = 0; nt < 8; nt++)
            acc[mh][nt] = (f32x4){0.f, 0.f, 0.f, 0.f};

    for (int kbase = 0; kbase < DD; kbase += 64) {
        __syncthreads();
        // A-frags: direct global loads (this chunk)
        f16x8 a_h[2][2], a_l[2][2]; // [kh][mh]
        #pragma unroll
        for (int kh = 0; kh < 2; kh++)
            #pragma unroll
            for (int mh = 0; mh < 2; mh++) {
                size_t o = arow + (size_t)(mh * 16) * DD + kbase + kh * 32;
                a_h[kh][mh] = __builtin_bit_cast(f16x8, *(const uint4*)(Xh + o));
                a_l[kh][mh] = __builtin_bit_cast(f16x8, *(const uint4*)(Xl + o));
            }
        // W tile 128n x 64k -> LDS (async DMA, linear dest, pre-swizzled source)
        #pragma unroll
        for (int j = 0; j < 4; j++) {
            gld16(Wth + wsrc0 + (size_t)j * 8 * DD + kbase, &WH[(wave * 32 + j * 8) * 64]);
            gld16(Wtl + wsrc0 + (size_t)j * 8 * DD + kbase, &WL[(wave * 32 + j * 8) * 64]);
        }
        asm volatile("s_waitcnt vmcnt(0)" ::: "memory");
        __syncthreads();

        #pragma unroll
        for (int kh = 0; kh < 2; kh++) {
            const int kg = ((kh * 4 + quad) ^ (ln & 7)) * 8; // swizzled read
            #pragma unroll
            for (int nt = 0; nt < 8; nt++) {
                const int n = nt * 16 + ln;
                f16x8 bh = __builtin_bit_cast(f16x8, *(const uint4*)&WH[n * 64 + kg]);
                f16x8 bl = __builtin_bit_cast(f16x8, *(const uint4*)&WL[n * 64 + kg]);
                #pragma unroll
                for (int mh = 0; mh < 2; mh++) {
                    acc[mh][nt] = __builtin_amdgcn_mfma_f32_16x16x32_f16(a_l[kh][mh], bh, acc[mh][nt], 0, 0, 0);
                    acc[mh][nt] = __builtin_amdgcn_mfma_f32_16x16x32_f16(a_h[kh][mh], bl, acc[mh][nt], 0, 0, 0);
                    acc[mh][nt] = __builtin_amdgcn_mfma_f32_16x16x32_f16(a_h[kh][mh], bh, acc[mh][nt], 0, 0, 0);
                }
            }
        }
    }

    // ---- epilogue: fp16 store to [B,H,S,DK] ----
    #pragma unroll
    for (int mh = 0; mh < 2; mh++)
        #pragma unroll
        for (int r = 0; r < 4; r++) {
            int m = m0 + wave * 32 + mh * 16 + quad * 4 + r;
            int b = m >> 11, s = m & 2047;
            #pragma unroll
            for (int nt = 0; nt < 8; nt++) {
                int head = h0 + (nt >> 2);
                u16* op = out + (((size_t)(b * HH + head) * SS + s)) * DKK;
                op[(nt & 3) * 16 + ln] = f2h(acc[mh][nt][r]);
            }
        }
}

// ---------------- stage 2: fp16 MFMA flash attention v4 ----------------
// 512 blocks x 512 threads (8 waves). Block p: bh = (p>>6)*8 + (p&7)
// (XCD affinity), pairidx = (p>>3)&7. Block processes q-tiles 15-pairidx
// (heavy) then pairidx -> constant 34 tile-iters/block. Per-row math
// identical to round-9.
__global__ __launch_bounds__(512) void attn_kernel(
    const u16* __restrict__ qb, const u16* __restrict__ kb,
    const u16* __restrict__ vb, u16* __restrict__ cath, u16* __restrict__ catl)
{
    __shared__ __align__(16) u16 Kt[64 * 72];
    __shared__ __align__(16) u16 Vt[64 * 72];
    __shared__ __align__(16) u16 Pw[8][16 * 72];

    const int tid  = threadIdx.x;
    const int lane = tid & 63, wave = tid >> 6; // 8 waves
    const int quad = lane >> 4, ln = lane & 15;

    const int p  = blockIdx.x;
    const int bh = (p >> 6) * 8 + (p & 7);
    const int pairidx = (p >> 3) & 7;
    const int b = bh >> 4, h = bh & 15;

    // staging maps (512 threads): K 1x uint4/thread, V 8 u16/thread (transpose)
    const int skey = tid >> 3, sseg = (tid & 7) * 8;
    const int vkey = tid & 63, vdkb = (tid >> 6) * 8;

    const u16* kbp = kb + (size_t)bh * SS * DKK;
    const u16* vbp = vb + (size_t)bh * SS * DKK;

    #pragma unroll 1
    for (int half = 0; half < 2; half++) {
        const int xt = half == 0 ? 15 - pairidx : pairidx;
        const int qbase = xt * 128;
        const int ktmax = 2 * xt + 1;

        const int wq = qbase + wave * 16;  // wave's first q row
        const int diagkt = wq >> 6;        // kv tile containing wave's diagonal
        const int wqmax = wq + 15;

        const u16* qp = qb + ((size_t)bh * SS + wq + ln) * DKK;
        f16x8 qf0 = __builtin_bit_cast(f16x8, *(const uint4*)(qp + quad * 8));
        f16x8 qf1 = __builtin_bit_cast(f16x8, *(const uint4*)(qp + 32 + quad * 8));

        f32x4 acc[4];
        #pragma unroll
        for (int n = 0; n < 4; n++) acc[n] = (f32x4){0.f, 0.f, 0.f, 0.f};
        float mrow[4], lrow[4];
        #pragma unroll
        for (int r = 0; r < 4; r++) { mrow[r] = -INFINITY; lrow[r] = 0.f; }

        // prologue: stage tile 0 (all waves must be past previous half's reads;
        // guaranteed by the trailing __syncthreads of the kt loop)
        {
            uint4 ka = *(const uint4*)(kbp + (size_t)skey * DKK + sseg);
            uint4 va = *(const uint4*)(vbp + (size_t)vkey * DKK + vdkb);
            *(uint4*)&Kt[skey * 72 + sseg] = ka;
            u16 vv[8];
            *(uint4*)&vv[0] = va;
            #pragma unroll
            for (int i = 0; i < 8; i++)
                Vt[(vdkb + i) * 72 + vkey] = vv[i];
        }
        __syncthreads();

        for (int kt = 0; kt <= ktmax; ++kt) {
            // prefetch next tile into registers
            uint4 ka, va;
            const bool pfb = (kt < ktmax);
            if (pfb) {
                ka = *(const uint4*)(kbp + (size_t)((kt + 1) * 64 + skey) * DKK + sseg);
                va = *(const uint4*)(vbp + (size_t)((kt + 1) * 64 + vkey) * DKK + vdkb);
            }

            if (kt * 64 <= wqmax) { // wave has unmasked keys in this tile
                f32x4 sa[4];
                #pragma unroll
                for (int n = 0; n < 4; n++) {
                    sa[n] = (f32x4){0.f, 0.f, 0.f, 0.f};
                    f16x8 kf0 = __builtin_bit_cast(f16x8,
                        *(const uint4*)&Kt[(n * 16 + ln) * 72 + quad * 8]);
                    sa[n] = __builtin_amdgcn_mfma_f32_16x16x32_f16(qf0, kf0, sa[n], 0, 0, 0);
                    f16x8 kf1 = __builtin_bit_cast(f16x8,
                        *(const uint4*)&Kt[(n * 16 + ln) * 72 + 32 + quad * 8]);
                    sa[n] = __builtin_amdgcn_mfma_f32_16x16x32_f16(qf1, kf1, sa[n], 0, 0, 0);
                }

                float sc[4][4];
                const bool diag = (kt == diagkt);
                #pragma unroll
                for (int n = 0; n < 4; n++)
                    #pragma unroll
                    for (int r = 0; r < 4; r++) {
                        float s = sa[n][r] * 8.0f;
                        if (diag && (kt * 64 + n * 16 + ln) > (wq + quad * 4 + r))
                            s = -INFINITY;
                        sc[n][r] = s;
                    }

                float rmax[4];
                #pragma unroll
                for (int r = 0; r < 4; r++)
                    rmax[r] = fmaxf(fmaxf(sc[0][r], sc[1][r]), fmaxf(sc[2][r], sc[3][r]));
                #pragma unroll
                for (int off = 1; off < 16; off <<= 1)
                    #pragma unroll
                    for (int r = 0; r < 4; r++)
                        rmax[r] = fmaxf(rmax[r], __shfl_xor(rmax[r], off));
                float alpha[4];
                #pragma unroll
                for (int r = 0; r < 4; r++) {
                    float mn = fmaxf(mrow[r], rmax[r]);
                    alpha[r] = __expf(mrow[r] - mn);
                    mrow[r] = mn;
                }
                u16* pw = Pw[wave];
                float lsum[4] = {0.f, 0.f, 0.f, 0.f};
                #pragma unroll
                for (int n = 0; n < 4; n++)
                    #pragma unroll
                    for (int r = 0; r < 4; r++) {
                        float pp = __expf(sc[n][r] - mrow[r]);
                        _Float16 ph = (_Float16)pp;
                        pw[(quad * 4 + r) * 72 + n * 16 + ln] = __builtin_bit_cast(u16, ph);
                        lsum[r] += (float)ph;
                    }
                #pragma unroll
                for (int off = 1; off < 16; off <<= 1)
                    #pragma unroll
                    for (int r = 0; r < 4; r++)
                        lsum[r] += __shfl_xor(lsum[r], off);
                #pragma unroll
                for (int r = 0; r < 4; r++)
                    lrow[r] = lrow[r] * alpha[r] + lsum[r];
                #pragma unroll
                for (int n = 0; n < 4; n++)
                    #pragma unroll
                    for (int r = 0; r < 4; r++)
                        acc[n][r] *= alpha[r];

                asm volatile("s_waitcnt lgkmcnt(0)" ::: "memory"); // wave-local RAW
                f16x8 pf0 = __builtin_bit_cast(f16x8, *(const uint4*)&pw[ln * 72 + quad * 8]);
                f16x8 pf1 = __builtin_bit_cast(f16x8, *(const uint4*)&pw[ln * 72 + 32 + quad * 8]);

                #pragma unroll
                for (int n = 0; n < 4; n++) {
                    f16x8 vf0 = __builtin_bit_cast(f16x8,
                        *(const uint4*)&Vt[(n * 16 + ln) * 72 + quad * 8]);
                    acc[n] = __builtin_amdgcn_mfma_f32_16x16x32_f16(pf0, vf0, acc[n], 0, 0, 0);
                    f16x8 vf1 = __builtin_bit_cast(f16x8,
                        *(const uint4*)&Vt[(n * 16 + ln) * 72 + 32 + quad * 8]);
                    acc[n] = __builtin_amdgcn_mfma_f32_16x16x32_f16(pf1, vf1, acc[n], 0, 0, 0);
                }
            }

            __syncthreads(); // all waves done reading Kt/Vt
            if (pfb) {
                *(uint4*)&Kt[skey * 72 + sseg] = ka;
                u16 vv[8];
                *(uint4*)&vv[0] = va;
                #pragma unroll
                for (int i = 0; i < 8; i++)
                    Vt[(vdkb + i) * 72 + vkey] = vv[i];
            }
            __syncthreads(); // next tile staged
        }

        #pragma unroll
        for (int r = 0; r < 4; r++) {
            float inv = 1.0f / lrow[r];
            int row = wq + quad * 4 + r;
            size_t o = ((size_t)b * SS + row) * DD + h * DKK;
            #pragma unroll
            for (int n = 0; n < 4; n++) {
                float v = acc[n][r] * inv;
                u16 hh, ll;
                split1(v, hh, ll);
                cath[o + n * 16 + ln] = hh;
                catl[o + n * 16 + ln] = ll;
            }
        }
    }
}

// ---------------- stage 3: outproj v3 (BN=128) ----------------
__global__ __launch_bounds__(256, 4) void outproj_v3_kernel(
    const u16* __restrict__ Ah, const u16* __restrict__ Al,
    const u16* __restrict__ Woh, const u16* __restrict__ Wol,
    const void* __restrict__ bo, const int* __restrict__ flags,
    float* __restrict__ out)
{
    const int n0 = blockIdx.y * 128;
    const int m0 = blockIdx.x * 128;

    __shared__ __align__(16) u16 WH[128 * 64];
    __shared__ __align__(16) u16 WL[128 * 64];

    const int tid  = threadIdx.x;
    const int lane = tid & 63, wave = tid >> 6;
    const int quad = lane >> 4, ln = lane & 15;

    const int lr = lane >> 3, lg = (lane & 7) ^ (lane >> 3);
    const size_t wsrc0 = ((size_t)(n0 + wave * 32 + lr)) * DD + lg * 8;
    const size_t arow  = (size_t)(m0 + wave * 32 + ln) * DD + quad * 8;

    f32x4 acc[2][8];
    #pragma unroll
    for (int mh = 0; mh < 2; mh++)
        #pragma unroll
        for (int nt = 0; nt < 8; nt++)
            acc[mh][nt] = (f32x4){0.f, 0.f, 0.f, 0.f};

    for (int kbase = 0; kbase < DD; kbase += 64) {
        __syncthreads();
        f16x8 a_h[2][2], a_l[2][2];
        #pragma unroll
        for (int kh = 0; kh < 2; kh++)
            #pragma unroll
            for (int mh = 0; mh < 2; mh++) {
                size_t o = arow + (size_t)(mh * 16) * DD + kbase + kh * 32;
                a_h[kh][mh] = __builtin_bit_cast(f16x8, *(const uint4*)(Ah + o));
                a_l[kh][mh] = __builtin_bit_cast(f16x8, *(const uint4*)(Al + o));
            }
        #pragma unroll
        for (int j = 0; j < 4; j++) {
            gld16(Woh + wsrc0 + (size_t)j * 8 * DD + kbase, &WH[(wave * 32 + j * 8) * 64]);
            gld16(Wol + wsrc0 + (size_t)j * 8 * DD + kbase, &WL[(wave * 32 + j * 8) * 64]);
        }
        asm volatile("s_waitcnt vmcnt(0)" ::: "memory");
        __syncthreads();

        #pragma unroll
        for (int kh = 0; kh < 2; kh++) {
            const int kg = ((kh * 4 + quad) ^ (ln & 7)) * 8;
            #pragma unroll
            for (int nt = 0; nt < 8; nt++) {
                const int n = nt * 16 + ln;
                f16x8 bh = __builtin_bit_cast(f16x8, *(const uint4*)&WH[n * 64 + kg]);
                f16x8 bl = __builtin_bit_cast(f16x8, *(const uint4*)&WL[n * 64 + kg]);
                #pragma unroll
                for (int mh = 0; mh < 2; mh++) {
                    acc[mh][nt] = __builtin_amdgcn_mfma_f32_16x16x32_f16(a_l[kh][mh], bh, acc[mh][nt], 0, 0, 0);
                    acc[mh][nt] = __builtin_amdgcn_mfma_f32_16x16x32_f16(a_h[kh][mh], bl, acc[mh][nt], 0, 0, 0);
                    acc[mh][nt] = __builtin_amdgcn_mfma_f32_16x16x32_f16(a_h[kh][mh], bh, acc[mh][nt], 0, 0, 0);
                }
            }
        }
    }

    const int bf = flags[7];
    float bias[8];
    #pragma unroll
    for (int nt = 0; nt < 8; nt++) {
        int n = n0 + nt * 16 + ln;
        bias[nt] = bf ? ((const float*)bo)[n] : bf2f(((const u16*)bo)[n]);
    }
    #pragma unroll
    for (int mh = 0; mh < 2; mh++)
        #pragma unroll
        for (int r = 0; r < 4; r++) {
            int m = m0 + wave * 32 + mh * 16 + quad * 4 + r;
            float* op = out + (size_t)m * DD + n0;
            #pragma unroll
            for (int nt = 0; nt < 8; nt++)
                op[nt * 16 + ln] = acc[mh][nt][r] + bias[nt];
        }
}

extern "C" void kernel_launch(void* const* d_in, const int* in_sizes, int n_in,
                              void* d_out, int out_size, void* d_ws, size_t ws_size,
                              hipStream_t stream)
{
    const void* Q = d_in[0];
    const void* K = d_in[1];
    const void* V = d_in[2];
    const int widx = (n_in >= 9) ? 4 : 3; // mask present iff n_in >= 9 (ignored)
    const void* Wq = d_in[widx + 0];
    const void* Wk = d_in[widx + 1];
    const void* Wv = d_in[widx + 2];
    const void* Wo = d_in[widx + 3];
    const void* bo = d_in[widx + 4];
    float* out = (float*)d_out;

    const size_t per = (size_t)BB * HH * SS * DKK; // 8,388,608 elements
    u16* qb = (u16*)d_ws;
    u16* kb = qb + per;
    u16* vb = kb + per;
    u16* xc = vb + per;          // 2*per region, dual-purpose:
    u16* Xh = xc;                //   during proj: X hi/lo
    u16* Xl = xc + per;
    u16* cath = xc;              //   after proj: cat hi/lo (attn output)
    u16* catl = xc + per;
    const size_t wtn = (size_t)3 * HH * DKK * DD; // 3,145,728
    u16* Wth = xc + 2 * per;
    u16* Wtl = Wth + wtn;
    u16* Woh = Wtl + wtn;
    u16* Wol = Woh + (size_t)DD * DD;
    int* flags = (int*)(Wol + (size_t)DD * DD);

    sniff_kernel<<<8, 64, 0, stream>>>(
        (const u16*)Q, (const u16*)K, (const u16*)V,
        (const u16*)Wq, (const u16*)Wk, (const u16*)Wv,
        (const u16*)Wo, (const u16*)bo, flags);

    split_wqkv_kernel<<<dim3(DD / 64, HH, 3), 256, 0, stream>>>(
        Wq, Wk, Wv, flags, Wth, Wtl);
    split_x_kernel<<<(DD * DD) / 2048, 256, 0, stream>>>(Wo, flags, 6, Woh, Wol);

    dim3 gp(MM / 128, HH / 2);
    split_x_kernel<<<(MM * DD) / 2048, 256, 0, stream>>>(Q, flags, 0, Xh, Xl);
    proj_v3_kernel<<<gp, 256, 0, stream>>>(Xh, Xl, Wth, Wtl, qb, 0);
    split_x_kernel<<<(MM * DD) / 2048, 256, 0, stream>>>(K, flags, 1, Xh, Xl);
    proj_v3_kernel<<<gp, 256, 0, stream>>>(Xh, Xl, Wth, Wtl, kb, 1);
    split_x_kernel<<<(MM * DD) / 2048, 256, 0, stream>>>(V, flags, 2, Xh, Xl);
    proj_v3_kernel<<<gp, 256, 0, stream>>>(Xh, Xl, Wth, Wtl, vb, 2);

    attn_kernel<<<(SS / 256) * BB * HH, 512, 0, stream>>>(qb, kb, vb, cath, catl);

    outproj_v3_kernel<<<dim3(MM / 128, DD / 128), 256, 0, stream>>>(
        cath, catl, Woh, Wol, bo, flags, out);
}

// Round 5
// 470.647 us; speedup vs baseline: 2.2232x; 1.0412x over previous
//
#include <hip/hip_runtime.h>
#include <math.h>

// MultiHeadAttention: B=4,S=2048,D=1024,H=16,DK=64
// Round 11:
//   attn v5: conflict-free LDS (row stride 64 u16 + XOR group swizzle, the
//     verified proj pattern) for Kt/Vt/Pw; double-buffered K/V -> ONE barrier
//     per tile-iter. Math bit-identical to round-10.
//   proj v4: 3 launches fused into one (blockIdx.z), A-operand hi/lo split
//     done in-kernel from original Q/K/V (same values) -> split_x kernels
//     for Q/K/V eliminated.
//   outproj v3 unchanged.

#define BB 4
#define SS 2048
#define DD 1024
#define HH 16
#define DKK 64
#define MM (BB * SS) // 8192

typedef unsigned short u16;
typedef _Float16 f16x8 __attribute__((ext_vector_type(8)));
typedef float f32x4 __attribute__((ext_vector_type(4)));
typedef __attribute__((address_space(1))) unsigned int gas_u32;
typedef __attribute__((address_space(3))) unsigned int las_u32;

__device__ __forceinline__ float bf2f(u16 u) {
    union { unsigned int i; float f; } c;
    c.i = ((unsigned int)u) << 16;
    return c.f;
}
__device__ __forceinline__ u16 f2h(float f) {
    _Float16 h = (_Float16)f; // RNE
    return __builtin_bit_cast(u16, h);
}
__device__ __forceinline__ void split1(float x, u16& hi, u16& lo) {
    _Float16 hh = (_Float16)x;
    hi = __builtin_bit_cast(u16, hh);
    lo = f2h(x - (float)hh);
}
// global(16B/lane) -> LDS at wave-uniform base + lane*16
__device__ __forceinline__ void gld16(const void* g, void* l) {
    __builtin_amdgcn_global_load_lds((gas_u32*)g, (las_u32*)l, 16, 0, 0);
}

// ---------------- stage 0: dtype sniffer (insurance) ----------------
__global__ void sniff_kernel(const u16* t0, const u16* t1, const u16* t2,
                             const u16* t3, const u16* t4, const u16* t5,
                             const u16* t6, const u16* t7, int* flags)
{
    const u16* ptrs[8] = {t0, t1, t2, t3, t4, t5, t6, t7};
    const u16* p = ptrs[blockIdx.x];
    int tid = threadIdx.x; // 64
    int cnt = 0;
    #pragma unroll
    for (int i = 0; i < 8; i++) {
        u16 v = p[tid * 8 + i];
        int e = (v >> 7) & 0xFF;
        if (e >= 0xF0 || (e <= 0x0F && (v & 0x7FFF) != 0)) cnt++;
    }
    #pragma unroll
    for (int off = 32; off; off >>= 1) cnt += __shfl_down(cnt, off);
    if (tid == 0) flags[blockIdx.x] = (cnt >= 4) ? 1 : 0;
}

// ---------------- stage 0.5a: elementwise hi/lo split (Wo only now) --------
__global__ __launch_bounds__(256) void split_x_kernel(
    const void* __restrict__ X, const int* __restrict__ flags, int fidx,
    u16* __restrict__ Xh, u16* __restrict__ Xl)
{
    const int xf = flags[fidx];
    size_t idx = ((size_t)blockIdx.x * 256 + threadIdx.x) * 8;
    float x[8];
    if (xf) {
        float4 a = *(const float4*)((const float*)X + idx);
        float4 b = *(const float4*)((const float*)X + idx + 4);
        x[0] = a.x; x[1] = a.y; x[2] = a.z; x[3] = a.w;
        x[4] = b.x; x[5] = b.y; x[6] = b.z; x[7] = b.w;
    } else {
        ushort4 a = *(const ushort4*)((const u16*)X + idx);
        ushort4 b = *(const ushort4*)((const u16*)X + idx + 4);
        x[0] = bf2f(a.x); x[1] = bf2f(a.y); x[2] = bf2f(a.z); x[3] = bf2f(a.w);
        x[4] = bf2f(b.x); x[5] = bf2f(b.y); x[6] = bf2f(b.z); x[7] = bf2f(b.w);
    }
    union { u16 u[8]; uint4 v; } H, L;
    #pragma unroll
    for (int i = 0; i < 8; i++) split1(x[i], H.u[i], L.u[i]);
    *(uint4*)(Xh + idx) = H.v;
    *(uint4*)(Xl + idx) = L.v;
}

// ---------------- stage 0.5b: Wq/Wk/Wv transpose + split ----------------
__global__ __launch_bounds__(256) void split_wqkv_kernel(
    const void* __restrict__ Wq, const void* __restrict__ Wk, const void* __restrict__ Wv,
    const int* __restrict__ flags, u16* __restrict__ Wth, u16* __restrict__ Wtl)
{
    const int z = blockIdx.z, h = blockIdx.y, kc = blockIdx.x;
    const void* __restrict__ W = (z == 0) ? Wq : (z == 1) ? Wk : Wv;
    const int wf = flags[3 + z];
    __shared__ float T[64][65];
    const int t = threadIdx.x;
    {
        const int kk = t >> 2, ns = (t & 3) * 16;
        const size_t base = (size_t)h * DD * DKK + (size_t)(kc * 64 + kk) * DKK + ns;
        #pragma unroll
        for (int j = 0; j < 4; j++) {
            if (wf) {
                float4 v = *(const float4*)((const float*)W + base + 4 * j);
                T[kk][ns + 4 * j + 0] = v.x; T[kk][ns + 4 * j + 1] = v.y;
                T[kk][ns + 4 * j + 2] = v.z; T[kk][ns + 4 * j + 3] = v.w;
            } else {
                ushort4 v = *(const ushort4*)((const u16*)W + base + 4 * j);
                T[kk][ns + 4 * j + 0] = bf2f(v.x); T[kk][ns + 4 * j + 1] = bf2f(v.y);
                T[kk][ns + 4 * j + 2] = bf2f(v.z); T[kk][ns + 4 * j + 3] = bf2f(v.w);
            }
        }
    }
    __syncthreads();
    {
        const int n = t >> 2, ks = (t & 3) * 16;
        union { u16 u[16]; uint4 v[2]; } Hv, Lv;
        #pragma unroll
        for (int i = 0; i < 16; i++) split1(T[ks + i][n], Hv.u[i], Lv.u[i]);
        size_t ob = ((size_t)(z * HH + h) * DKK + n) * DD + kc * 64 + ks;
        *(uint4*)(Wth + ob)     = Hv.v[0];
        *(uint4*)(Wth + ob + 8) = Hv.v[1];
        *(uint4*)(Wtl + ob)     = Lv.v[0];
        *(uint4*)(Wtl + ob + 8) = Lv.v[1];
    }
}

// ---------------- stage 1: proj v4 (fused z, in-kernel A split) ----------------
// grid (MM/128, HH/2, 3), block 256 (4 waves). BN=128 (2 heads).
__global__ __launch_bounds__(256, 4) void proj_v4_kernel(
    const void* __restrict__ Q, const void* __restrict__ K, const void* __restrict__ V,
    const u16* __restrict__ Wth, const u16* __restrict__ Wtl,
    const int* __restrict__ flags,
    u16* __restrict__ qb, u16* __restrict__ kb, u16* __restrict__ vb)
{
    const int z = blockIdx.z;
    const void* __restrict__ X = (z == 0) ? Q : (z == 1) ? K : V;
    u16* __restrict__ out      = (z == 0) ? qb : (z == 1) ? kb : vb;
    const int xf = flags[z];
    const int h0 = blockIdx.y * 2;
    const int m0 = blockIdx.x * 128;

    __shared__ __align__(16) u16 WH[128 * 64];
    __shared__ __align__(16) u16 WL[128 * 64];

    const int tid  = threadIdx.x;
    const int lane = tid & 63, wave = tid >> 6;
    const int quad = lane >> 4, ln = lane & 15;

    const int lr = lane >> 3, lg = (lane & 7) ^ (lane >> 3);
    const size_t wsrc0 = ((size_t)((z * HH + h0) * DKK) + wave * 32 + lr) * DD + lg * 8;
    const size_t arow = (size_t)(m0 + wave * 32 + ln) * DD + quad * 8;

    f32x4 acc[2][8];
    #pragma unroll
    for (int mh = 0; mh < 2; mh++)
        #pragma unroll
        for (int nt = 0; nt < 8; nt++)
            acc[mh][nt] = (f32x4){0.f, 0.f, 0.f, 0.f};

    for (int kbase = 0; kbase < DD; kbase += 64) {
        __syncthreads();
        // A-frags: load fp32/bf16 source, split hi/lo in-register
        f16x8 a_h[2][2], a_l[2][2]; // [kh][mh]
        #pragma unroll
        for (int kh = 0; kh < 2; kh++)
            #pragma unroll
            for (int mh = 0; mh < 2; mh++) {
                size_t o = arow + (size_t)(mh * 16) * DD + kbase + kh * 32;
                float x[8];
                if (xf) {
                    float4 a = *(const float4*)((const float*)X + o);
                    float4 b = *(const float4*)((const float*)X + o + 4);
                    x[0] = a.x; x[1] = a.y; x[2] = a.z; x[3] = a.w;
                    x[4] = b.x; x[5] = b.y; x[6] = b.z; x[7] = b.w;
                } else {
                    ushort4 a = *(const ushort4*)((const u16*)X + o);
                    ushort4 b = *(const ushort4*)((const u16*)X + o + 4);
                    x[0] = bf2f(a.x); x[1] = bf2f(a.y); x[2] = bf2f(a.z); x[3] = bf2f(a.w);
                    x[4] = bf2f(b.x); x[5] = bf2f(b.y); x[6] = bf2f(b.z); x[7] = bf2f(b.w);
                }
                union { u16 u[8]; f16x8 v; } H, L;
                #pragma unroll
                for (int i = 0; i < 8; i++) split1(x[i], H.u[i], L.u[i]);
                a_h[kh][mh] = H.v;
                a_l[kh][mh] = L.v;
            }
        // W tile 128n x 64k -> LDS (async DMA, linear dest, pre-swizzled source)
        #pragma unroll
        for (int j = 0; j < 4; j++) {
            gld16(Wth + wsrc0 + (size_t)j * 8 * DD + kbase, &WH[(wave * 32 + j * 8) * 64]);
            gld16(Wtl + wsrc0 + (size_t)j * 8 * DD + kbase, &WL[(wave * 32 + j * 8) * 64]);
        }
        asm volatile("s_waitcnt vmcnt(0)" ::: "memory");
        __syncthreads();

        #pragma unroll
        for (int kh = 0; kh < 2; kh++) {
            const int kg = ((kh * 4 + quad) ^ (ln & 7)) * 8; // swizzled read
            #pragma unroll
            for (int nt = 0; nt < 8; nt++) {
                const int n = nt * 16 + ln;
                f16x8 bh = __builtin_bit_cast(f16x8, *(const uint4*)&WH[n * 64 + kg]);
                f16x8 bl = __builtin_bit_cast(f16x8, *(const uint4*)&WL[n * 64 + kg]);
                #pragma unroll
                for (int mh = 0; mh < 2; mh++) {
                    acc[mh][nt] = __builtin_amdgcn_mfma_f32_16x16x32_f16(a_l[kh][mh], bh, acc[mh][nt], 0, 0, 0);
                    acc[mh][nt] = __builtin_amdgcn_mfma_f32_16x16x32_f16(a_h[kh][mh], bl, acc[mh][nt], 0, 0, 0);
                    acc[mh][nt] = __builtin_amdgcn_mfma_f32_16x16x32_f16(a_h[kh][mh], bh, acc[mh][nt], 0, 0, 0);
                }
            }
        }
    }

    // ---- epilogue: fp16 store to [B,H,S,DK] ----
    #pragma unroll
    for (int mh = 0; mh < 2; mh++)
        #pragma unroll
        for (int r = 0; r < 4; r++) {
            int m = m0 + wave * 32 + mh * 16 + quad * 4 + r;
            int b = m >> 11, s = m & 2047;
            #pragma unroll
            for (int nt = 0; nt < 8; nt++) {
                int head = h0 + (nt >> 2);
                u16* op = out + (((size_t)(b * HH + head) * SS + s)) * DKK;
                op[(nt & 3) * 16 + ln] = f2h(acc[mh][nt][r]);
            }
        }
}

// ---------------- stage 2: fp16 MFMA flash attention v5 ----------------
// 512 blocks x 512 threads (8 waves). Paired q-tiles (15-i, i) -> constant
// work. Conflict-free swizzled LDS ([row][64] u16, group g at g^(row&7)),
// double-buffered K/V, one barrier per tile-iter.
__global__ __launch_bounds__(512) void attn_kernel(
    const u16* __restrict__ qb, const u16* __restrict__ kb,
    const u16* __restrict__ vb, u16* __restrict__ cath, u16* __restrict__ catl)
{
    __shared__ __align__(16) u16 Kt[2][64 * 64];
    __shared__ __align__(16) u16 Vt[2][64 * 64];
    __shared__ __align__(16) u16 Pw[8][16 * 64];

    const int tid  = threadIdx.x;
    const int lane = tid & 63, wave = tid >> 6; // 8 waves
    const int quad = lane >> 4, ln = lane & 15;

    const int p  = blockIdx.x;
    const int bh = (p >> 6) * 8 + (p & 7);
    const int pairidx = (p >> 3) & 7;
    const int b = bh >> 4, h = bh & 15;

    // staging maps (512 threads)
    const int skey = tid >> 3, kgrp = tid & 7;              // K: 1 uint4/thread
    const int koff = skey * 64 + ((kgrp ^ (skey & 7)) << 3);
    const int vkey = tid & 63, vdkb = (tid >> 6) * 8;       // V: 8 u16/thread (transpose)

    const u16* kbp = kb + (size_t)bh * SS * DKK;
    const u16* vbp = vb + (size_t)bh * SS * DKK;

    #pragma unroll 1
    for (int half = 0; half < 2; half++) {
        const int xt = half == 0 ? 15 - pairidx : pairidx;
        const int qbase = xt * 128;
        const int ktmax = 2 * xt + 1;

        const int wq = qbase + wave * 16;  // wave's first q row
        const int diagkt = wq >> 6;        // kv tile containing wave's diagonal
        const int wqmax = wq + 15;

        const u16* qp = qb + ((size_t)bh * SS + wq + ln) * DKK;
        f16x8 qf0 = __builtin_bit_cast(f16x8, *(const uint4*)(qp + quad * 8));
        f16x8 qf1 = __builtin_bit_cast(f16x8, *(const uint4*)(qp + 32 + quad * 8));

        f32x4 acc[4];
        #pragma unroll
        for (int n = 0; n < 4; n++) acc[n] = (f32x4){0.f, 0.f, 0.f, 0.f};
        float mrow[4], lrow[4];
        #pragma unroll
        for (int r = 0; r < 4; r++) { mrow[r] = -INFINITY; lrow[r] = 0.f; }

        // prologue: stage tile 0 into buffer 0 (prev iter's trailing barrier
        // guarantees no outstanding readers)
        {
            uint4 ka = *(const uint4*)(kbp + (size_t)skey * DKK + kgrp * 8);
            uint4 va = *(const uint4*)(vbp + (size_t)vkey * DKK + vdkb);
            *(uint4*)&Kt[0][koff] = ka;
            u16 vv[8];
            *(uint4*)&vv[0] = va;
            #pragma unroll
            for (int i = 0; i < 8; i++) {
                int row = vdkb + i;
                Vt[0][row * 64 + (((vkey >> 3) ^ (row & 7)) << 3) + (vkey & 7)] = vv[i];
            }
        }
        __syncthreads();

        int cur = 0;
        for (int kt = 0; kt <= ktmax; ++kt) {
            // prefetch next tile into registers
            uint4 ka, va;
            const bool pfb = (kt < ktmax);
            if (pfb) {
                ka = *(const uint4*)(kbp + (size_t)((kt + 1) * 64 + skey) * DKK + kgrp * 8);
                va = *(const uint4*)(vbp + (size_t)((kt + 1) * 64 + vkey) * DKK + vdkb);
            }

            if (kt * 64 <= wqmax) { // wave has unmasked keys in this tile
                const u16* KT = Kt[cur];
                const u16* VT = Vt[cur];
                f32x4 sa[4];
                #pragma unroll
                for (int n = 0; n < 4; n++) {
                    sa[n] = (f32x4){0.f, 0.f, 0.f, 0.f};
                    const int krow = n * 16 + ln;
                    f16x8 kf0 = __builtin_bit_cast(f16x8,
                        *(const uint4*)&KT[krow * 64 + ((quad ^ (ln & 7)) << 3)]);
                    sa[n] = __builtin_amdgcn_mfma_f32_16x16x32_f16(qf0, kf0, sa[n], 0, 0, 0);
                    f16x8 kf1 = __builtin_bit_cast(f16x8,
                        *(const uint4*)&KT[krow * 64 + (((quad + 4) ^ (ln & 7)) << 3)]);
                    sa[n] = __builtin_amdgcn_mfma_f32_16x16x32_f16(qf1, kf1, sa[n], 0, 0, 0);
                }

                float sc[4][4];
                const bool diag = (kt == diagkt);
                #pragma unroll
                for (int n = 0; n < 4; n++)
                    #pragma unroll
                    for (int r = 0; r < 4; r++) {
                        float s = sa[n][r] * 8.0f;
                        if (diag && (kt * 64 + n * 16 + ln) > (wq + quad * 4 + r))
                            s = -INFINITY;
                        sc[n][r] = s;
                    }

                float rmax[4];
                #pragma unroll
                for (int r = 0; r < 4; r++)
                    rmax[r] = fmaxf(fmaxf(sc[0][r], sc[1][r]), fmaxf(sc[2][r], sc[3][r]));
                #pragma unroll
                for (int off = 1; off < 16; off <<= 1)
                    #pragma unroll
                    for (int r = 0; r < 4; r++)
                        rmax[r] = fmaxf(rmax[r], __shfl_xor(rmax[r], off));
                float alpha[4];
                #pragma unroll
                for (int r = 0; r < 4; r++) {
                    float mn = fmaxf(mrow[r], rmax[r]);
                    alpha[r] = __expf(mrow[r] - mn);
                    mrow[r] = mn;
                }
                u16* pw = Pw[wave];
                float lsum[4] = {0.f, 0.f, 0.f, 0.f};
                #pragma unroll
                for (int n = 0; n < 4; n++)
                    #pragma unroll
                    for (int r = 0; r < 4; r++) {
                        float pp = __expf(sc[n][r] - mrow[r]);
                        _Float16 ph = (_Float16)pp;
                        const int row = quad * 4 + r;
                        pw[row * 64 + (((n * 2 + (ln >> 3)) ^ (row & 7)) << 3) + (ln & 7)]
                            = __builtin_bit_cast(u16, ph);
                        lsum[r] += (float)ph;
                    }
                #pragma unroll
                for (int off = 1; off < 16; off <<= 1)
                    #pragma unroll
                    for (int r = 0; r < 4; r++)
                        lsum[r] += __shfl_xor(lsum[r], off);
                #pragma unroll
                for (int r = 0; r < 4; r++)
                    lrow[r] = lrow[r] * alpha[r] + lsum[r];
                #pragma unroll
                for (int n = 0; n < 4; n++)
                    #pragma unroll
                    for (int r = 0; r < 4; r++)
                        acc[n][r] *= alpha[r];

                asm volatile("s_waitcnt lgkmcnt(0)" ::: "memory"); // wave-local RAW
                f16x8 pf0 = __builtin_bit_cast(f16x8,
                    *(const uint4*)&pw[ln * 64 + ((quad ^ (ln & 7)) << 3)]);
                f16x8 pf1 = __builtin_bit_cast(f16x8,
                    *(const uint4*)&pw[ln * 64 + (((quad + 4) ^ (ln & 7)) << 3)]);

                #pragma unroll
                for (int n = 0; n < 4; n++) {
                    const int vrow = n * 16 + ln;
                    f16x8 vf0 = __builtin_bit_cast(f16x8,
                        *(const uint4*)&VT[vrow * 64 + ((quad ^ (ln & 7)) << 3)]);
                    acc[n] = __builtin_amdgcn_mfma_f32_16x16x32_f16(pf0, vf0, acc[n], 0, 0, 0);
                    f16x8 vf1 = __builtin_bit_cast(f16x8,
                        *(const uint4*)&VT[vrow * 64 + (((quad + 4) ^ (ln & 7)) << 3)]);
                    acc[n] = __builtin_amdgcn_mfma_f32_16x16x32_f16(pf1, vf1, acc[n], 0, 0, 0);
                }
            }

            // write prefetched tile into the other buffer (fenced by the
            // PREVIOUS iteration's barrier), then one barrier
            if (pfb) {
                *(uint4*)&Kt[cur ^ 1][koff] = ka;
                u16 vv[8];
                *(uint4*)&vv[0] = va;
                #pragma unroll
                for (int i = 0; i < 8; i++) {
                    int row = vdkb + i;
                    Vt[cur ^ 1][row * 64 + (((vkey >> 3) ^ (row & 7)) << 3) + (vkey & 7)] = vv[i];
                }
            }
            __syncthreads();
            cur ^= 1;
        }

        #pragma unroll
        for (int r = 0; r < 4; r++) {
            float inv = 1.0f / lrow[r];
            int row = wq + quad * 4 + r;
            size_t o = ((size_t)b * SS + row) * DD + h * DKK;
            #pragma unroll
            for (int n = 0; n < 4; n++) {
                float v = acc[n][r] * inv;
                u16 hh, ll;
                split1(v, hh, ll);
                cath[o + n * 16 + ln] = hh;
                catl[o + n * 16 + ln] = ll;
            }
        }
    }
}

// ---------------- stage 3: outproj v3 (unchanged) ----------------
__global__ __launch_bounds__(256, 4) void outproj_v3_kernel(
    const u16* __restrict__ Ah, const u16* __restrict__ Al,
    const u16* __restrict__ Woh, const u16* __restrict__ Wol,
    const void* __restrict__ bo, const int* __restrict__ flags,
    float* __restrict__ out)
{
    const int n0 = blockIdx.y * 128;
    const int m0 = blockIdx.x * 128;

    __shared__ __align__(16) u16 WH[128 * 64];
    __shared__ __align__(16) u16 WL[128 * 64];

    const int tid  = threadIdx.x;
    const int lane = tid & 63, wave = tid >> 6;
    const int quad = lane >> 4, ln = lane & 15;

    const int lr = lane >> 3, lg = (lane & 7) ^ (lane >> 3);
    const size_t wsrc0 = ((size_t)(n0 + wave * 32 + lr)) * DD + lg * 8;
    const size_t arow  = (size_t)(m0 + wave * 32 + ln) * DD + quad * 8;

    f32x4 acc[2][8];
    #pragma unroll
    for (int mh = 0; mh < 2; mh++)
        #pragma unroll
        for (int nt = 0; nt < 8; nt++)
            acc[mh][nt] = (f32x4){0.f, 0.f, 0.f, 0.f};

    for (int kbase = 0; kbase < DD; kbase += 64) {
        __syncthreads();
        f16x8 a_h[2][2], a_l[2][2];
        #pragma unroll
        for (int kh = 0; kh < 2; kh++)
            #pragma unroll
            for (int mh = 0; mh < 2; mh++) {
                size_t o = arow + (size_t)(mh * 16) * DD + kbase + kh * 32;
                a_h[kh][mh] = __builtin_bit_cast(f16x8, *(const uint4*)(Ah + o));
                a_l[kh][mh] = __builtin_bit_cast(f16x8, *(const uint4*)(Al + o));
            }
        #pragma unroll
        for (int j = 0; j < 4; j++) {
            gld16(Woh + wsrc0 + (size_t)j * 8 * DD + kbase, &WH[(wave * 32 + j * 8) * 64]);
            gld16(Wol + wsrc0 + (size_t)j * 8 * DD + kbase, &WL[(wave * 32 + j * 8) * 64]);
        }
        asm volatile("s_waitcnt vmcnt(0)" ::: "memory");
        __syncthreads();

        #pragma unroll
        for (int kh = 0; kh < 2; kh++) {
            const int kg = ((kh * 4 + quad) ^ (ln & 7)) * 8;
            #pragma unroll
            for (int nt = 0; nt < 8; nt++) {
                const int n = nt * 16 + ln;
                f16x8 bh = __builtin_bit_cast(f16x8, *(const uint4*)&WH[n * 64 + kg]);
                f16x8 bl = __builtin_bit_cast(f16x8, *(const uint4*)&WL[n * 64 + kg]);
                #pragma unroll
                for (int mh = 0; mh < 2; mh++) {
                    acc[mh][nt] = __builtin_amdgcn_mfma_f32_16x16x32_f16(a_l[kh][mh], bh, acc[mh][nt], 0, 0, 0);
                    acc[mh][nt] = __builtin_amdgcn_mfma_f32_16x16x32_f16(a_h[kh][mh], bl, acc[mh][nt], 0, 0, 0);
                    acc[mh][nt] = __builtin_amdgcn_mfma_f32_16x16x32_f16(a_h[kh][mh], bh, acc[mh][nt], 0, 0, 0);
                }
            }
        }
    }

    const int bf = flags[7];
    float bias[8];
    #pragma unroll
    for (int nt = 0; nt < 8; nt++) {
        int n = n0 + nt * 16 + ln;
        bias[nt] = bf ? ((const float*)bo)[n] : bf2f(((const u16*)bo)[n]);
    }
    #pragma unroll
    for (int mh = 0; mh < 2; mh++)
        #pragma unroll
        for (int r = 0; r < 4; r++) {
            int m = m0 + wave * 32 + mh * 16 + quad * 4 + r;
            float* op = out + (size_t)m * DD + n0;
            #pragma unroll
            for (int nt = 0; nt < 8; nt++)
                op[nt * 16 + ln] = acc[mh][nt][r] + bias[nt];
        }
}

extern "C" void kernel_launch(void* const* d_in, const int* in_sizes, int n_in,
                              void* d_out, int out_size, void* d_ws, size_t ws_size,
                              hipStream_t stream)
{
    const void* Q = d_in[0];
    const void* K = d_in[1];
    const void* V = d_in[2];
    const int widx = (n_in >= 9) ? 4 : 3; // mask present iff n_in >= 9 (ignored)
    const void* Wq = d_in[widx + 0];
    const void* Wk = d_in[widx + 1];
    const void* Wv = d_in[widx + 2];
    const void* Wo = d_in[widx + 3];
    const void* bo = d_in[widx + 4];
    float* out = (float*)d_out;

    const size_t per = (size_t)BB * HH * SS * DKK; // 8,388,608 elements
    u16* qb = (u16*)d_ws;
    u16* kb = qb + per;
    u16* vb = kb + per;
    u16* cath = vb + per;
    u16* catl = cath + per;
    const size_t wtn = (size_t)3 * HH * DKK * DD; // 3,145,728
    u16* Wth = catl + per;
    u16* Wtl = Wth + wtn;
    u16* Woh = Wtl + wtn;
    u16* Wol = Woh + (size_t)DD * DD;
    int* flags = (int*)(Wol + (size_t)DD * DD);

    sniff_kernel<<<8, 64, 0, stream>>>(
        (const u16*)Q, (const u16*)K, (const u16*)V,
        (const u16*)Wq, (const u16*)Wk, (const u16*)Wv,
        (const u16*)Wo, (const u16*)bo, flags);

    split_wqkv_kernel<<<dim3(DD / 64, HH, 3), 256, 0, stream>>>(
        Wq, Wk, Wv, flags, Wth, Wtl);
    split_x_kernel<<<(DD * DD) / 2048, 256, 0, stream>>>(Wo, flags, 6, Woh, Wol);

    proj_v4_kernel<<<dim3(MM / 128, HH / 2, 3), 256, 0, stream>>>(
        Q, K, V, Wth, Wtl, flags, qb, kb, vb);

    attn_kernel<<<(SS / 256) * BB * HH, 512, 0, stream>>>(qb, kb, vb, cath, catl);

    outproj_v3_kernel<<<dim3(MM / 128, DD / 128), 256, 0, stream>>>(
        cath, catl, Woh, Wol, bo, flags, out);
}